// Round 1
// baseline (9677.076 us; speedup 1.0000x reference)
//
#include <hip/hip_runtime.h>
#include <stdint.h>

#define T_LEN 512
#define BATCH 64
#define EMB   512
#define HID   512
#define NTAG  23
#define NEGV  -10000.0f

typedef __attribute__((ext_vector_type(4))) float f32x4;
typedef __attribute__((ext_vector_type(8))) short short8;

#define DEVI __device__ __forceinline__

DEVI unsigned short f32_to_bf16_rn(float f) {
  union { float f; uint32_t u; } v; v.f = f;
  uint32_t u = v.u;
  uint32_t r = u + 0x7FFFu + ((u >> 16) & 1u);
  return (unsigned short)(r >> 16);
}
DEVI float bf16_to_f32(unsigned short h) {
  union { float f; uint32_t u; } v; v.u = ((uint32_t)h) << 16;
  return v.f;
}

DEVI f32x4 mfma16(short8 a, short8 b, f32x4 c) {
  return __builtin_amdgcn_mfma_f32_16x16x32_bf16(a, b, c, 0, 0, 0);
}

// device-coherent (cross-XCD) 16B load: bypass L1/L2 so we read LLC-fresh h
DEVI void ld_sc(const void* p, short8& d) {
  asm volatile("global_load_dwordx4 %0, %1, off sc0 sc1" : "=v"(d) : "v"(p));
}
DEVI void wait_all(short8& a0, short8& a1, short8& a2, short8& a3,
                   short8& b0, short8& b1, short8& b2, short8& b3) {
  asm volatile("s_waitcnt vmcnt(0)"
               : "+v"(a0), "+v"(a1), "+v"(a2), "+v"(a3),
                 "+v"(b0), "+v"(b1), "+v"(b2), "+v"(b3)
               :: "memory");
}
// write-through 2B store so h reaches LLC before the barrier arrival
DEVI void st_sc16(unsigned short* p, unsigned short v) {
  unsigned int vv = v;
  asm volatile("global_store_short %0, %1, off sc0 sc1" :: "v"(p), "v"(vv) : "memory");
}

// -------------------- fragment-layout packing kernels --------------------
// XF[t][mt4][kq16][lane64][8]  (A-frags of texts, hi/lo split)
__global__ __launch_bounds__(256) void prep_xf(const float* __restrict__ x,
                                               unsigned short* __restrict__ xf_hi,
                                               unsigned short* __restrict__ xf_lo) {
  int idx = blockIdx.x * 256 + threadIdx.x;       // 512*4*16*64 = 2097152
  int lane = idx & 63;
  int kq   = (idx >> 6) & 15;
  int mt   = (idx >> 10) & 3;
  int t    = idx >> 12;
  int b  = mt * 16 + (lane & 15);
  int e0 = kq * 32 + (lane >> 4) * 8;
  const float* src = x + ((size_t)b * T_LEN + t) * EMB + e0;
  size_t dst = (size_t)idx * 8;
#pragma unroll
  for (int i = 0; i < 8; ++i) {
    float v = src[i];
    unsigned short hi = f32_to_bf16_rn(v);
    unsigned short lo = f32_to_bf16_rn(v - bf16_to_f32(hi));
    xf_hi[dst + i] = hi;
    xf_lo[dst + i] = lo;
  }
}

// WF[dir2][mat2][js32][nt4][kq16][lane64][8]; mat0 = Whh, mat1 = Wih
__global__ __launch_bounds__(256) void prep_wf(const float* __restrict__ whh_f,
                                               const float* __restrict__ wih_f,
                                               const float* __restrict__ whh_b,
                                               const float* __restrict__ wih_b,
                                               unsigned short* __restrict__ wf_hi,
                                               unsigned short* __restrict__ wf_lo) {
  int idx = blockIdx.x * 256 + threadIdx.x;       // 2*2*32*4*16*64 = 524288
  int lane = idx & 63;
  int kq   = (idx >> 6) & 15;
  int nt   = (idx >> 10) & 3;
  int js   = (idx >> 12) & 31;
  int mat  = (idx >> 17) & 1;
  int dir  = (idx >> 18) & 1;
  const float* W = dir ? (mat ? wih_b : whh_b) : (mat ? wih_f : whh_f);
  int row = nt * 512 + js * 16 + (lane & 15);     // gate-major rows of [2048][512]
  int k0  = kq * 32 + (lane >> 4) * 8;
  const float* src = W + (size_t)row * 512 + k0;
  size_t dst = (size_t)idx * 8;
#pragma unroll
  for (int i = 0; i < 8; ++i) {
    float v = src[i];
    unsigned short hi = f32_to_bf16_rn(v);
    unsigned short lo = f32_to_bf16_rn(v - bf16_to_f32(hi));
    wf_hi[dst + i] = hi;
    wf_lo[dst + i] = lo;
  }
}

// W2T[nt2][kq32][lane64][8]  (B-frags of W_h2t [23][1024], N padded to 32)
__global__ __launch_bounds__(256) void prep_w2t(const float* __restrict__ w2t,
                                                unsigned short* __restrict__ o_hi,
                                                unsigned short* __restrict__ o_lo) {
  int idx = blockIdx.x * 256 + threadIdx.x;       // 2*32*64 = 4096
  int lane = idx & 63;
  int kq   = (idx >> 6) & 31;
  int nt   = (idx >> 11) & 1;
  int n  = nt * 16 + (lane & 15);
  int k0 = kq * 32 + (lane >> 4) * 8;
  size_t dst = (size_t)idx * 8;
#pragma unroll
  for (int i = 0; i < 8; ++i) {
    float v = (n < NTAG) ? w2t[(size_t)n * 1024 + k0 + i] : 0.0f;
    unsigned short hi = f32_to_bf16_rn(v);
    unsigned short lo = f32_to_bf16_rn(v - bf16_to_f32(hi));
    o_hi[dst + i] = hi;
    o_lo[dst + i] = lo;
  }
}

// -------------------- persistent BiLSTM recurrence --------------------
// Grid = 256 WGs, 1/CU. WG = (dir, js(16 j's), bq(16 batch rows)).
// HF[dir][slot 514][mt4][kq16][lane64][8] hi/lo; slot = t+1; slots 0,513 zeroed.
__global__ __launch_bounds__(256, 1)
void lstm_rec(const unsigned short* __restrict__ xf_hi,
              const unsigned short* __restrict__ xf_lo,
              const unsigned short* __restrict__ wf_hi,
              const unsigned short* __restrict__ wf_lo,
              const float* __restrict__ bias_f,
              const float* __restrict__ bias_b,
              unsigned short* __restrict__ hf_hi,
              unsigned short* __restrict__ hf_lo,
              unsigned int* counters) {
  extern __shared__ unsigned char smem[];
  unsigned short* w_lds = (unsigned short*)smem;            // [mat2][nt4][kq16][lane64][8] = 131072 B
  float* scratch = (float*)(smem + 131072);                 // [wave4][nt4][lane64][4] = 16384 B

  int wg  = blockIdx.x;
  int dir = wg >> 7;
  int js  = (wg >> 2) & 31;
  int bq  = wg & 3;
  int tid  = threadIdx.x;
  int wave = tid >> 6;
  int lane = tid & 63;

  // stage w_hi (both matrices) for this (dir, js) into LDS: 2 x 64KB contiguous blocks
  {
    const uint4* s0 = (const uint4*)wf_hi + (((size_t)(dir * 2 + 0) * 32 + js) * 4096);
    const uint4* s1 = (const uint4*)wf_hi + (((size_t)(dir * 2 + 1) * 32 + js) * 4096);
    uint4* d = (uint4*)w_lds;
    for (int i = tid; i < 4096; i += 256) { d[i] = s0[i]; d[4096 + i] = s1[i]; }
  }
  __syncthreads();

  int sm = tid >> 4;                 // local batch row 0..15
  int sj = tid & 15;                 // local j 0..15
  int jglob = js * 16 + sj;
  const float* bias = dir ? bias_b : bias_f;
  float bias_g[4];
#pragma unroll
  for (int g = 0; g < 4; ++g) bias_g[g] = bias[g * 512 + jglob];
  float c_state = 0.0f;

  // precompute h write address pieces
  int kqh   = jglob >> 5;
  int lane2 = ((jglob >> 3) & 3) * 16 + sm;
  int jrem  = jglob & 7;

  for (int s = 0; s < T_LEN; ++s) {
    int t = dir ? (T_LEN - 1 - s) : s;
    int rslot = dir ? (t + 2) : t;   // h[t+1] (bwd) / h[t-1] (fwd); zeros at s==0

    f32x4 acc[4];
#pragma unroll
    for (int nt = 0; nt < 4; ++nt) { f32x4 z = {0.f, 0.f, 0.f, 0.f}; acc[nt] = z; }

    // issue coherent h-frag loads first (hide LLC latency under the x-GEMM)
    short8 hh[4], hl[4];
    {
      const short8* bh = (const short8*)hf_hi + ((((size_t)dir * 514 + rslot) * 4 + bq) * 16) * 64;
      const short8* bl = (const short8*)hf_lo + ((((size_t)dir * 514 + rslot) * 4 + bq) * 16) * 64;
#pragma unroll
      for (int q = 0; q < 4; ++q) {
        int kq = wave * 4 + q;
        ld_sc((const void*)(bh + kq * 64 + lane), hh[q]);
        ld_sc((const void*)(bl + kq * 64 + lane), hl[q]);
      }
    }

    // x-part GEMM (mat=1), plain cached loads
#pragma unroll
    for (int q = 0; q < 4; ++q) {
      int kq = wave * 4 + q;
      size_t xoff = ((((size_t)t * 4 + bq) * 16 + kq) * 64 + lane) * 8;
      short8 xh = *(const short8*)(xf_hi + xoff);
      short8 xl = *(const short8*)(xf_lo + xoff);
#pragma unroll
      for (int nt = 0; nt < 4; ++nt) {
        short8 bh = *(const short8*)&w_lds[((((size_t)(1 * 4 + nt)) * 16 + kq) * 64 + lane) * 8];
        short8 bl = *(const short8*)(wf_lo +
              ((((((size_t)dir * 2 + 1) * 32 + js) * 4 + nt) * 16 + kq) * 64 + lane) * 8);
        acc[nt] = mfma16(xh, bh, acc[nt]);
        acc[nt] = mfma16(xh, bl, acc[nt]);
        acc[nt] = mfma16(xl, bh, acc[nt]);
      }
    }

    wait_all(hh[0], hh[1], hh[2], hh[3], hl[0], hl[1], hl[2], hl[3]);

    // h-part GEMM (mat=0)
#pragma unroll
    for (int q = 0; q < 4; ++q) {
      int kq = wave * 4 + q;
#pragma unroll
      for (int nt = 0; nt < 4; ++nt) {
        short8 bh = *(const short8*)&w_lds[((((size_t)(0 * 4 + nt)) * 16 + kq) * 64 + lane) * 8];
        short8 bl = *(const short8*)(wf_lo +
              ((((((size_t)dir * 2 + 0) * 32 + js) * 4 + nt) * 16 + kq) * 64 + lane) * 8);
        acc[nt] = mfma16(hh[q], bh, acc[nt]);
        acc[nt] = mfma16(hh[q], bl, acc[nt]);
        acc[nt] = mfma16(hl[q], bh, acc[nt]);
      }
    }

    // cross-wave K-reduction via LDS
#pragma unroll
    for (int nt = 0; nt < 4; ++nt)
      *(f32x4*)&scratch[((size_t)(wave * 4 + nt) * 64 + lane) * 4] = acc[nt];
    __syncthreads();

    int lidx = (((sm >> 2) * 16) + sj) * 4 + (sm & 3);
    float g4[4];
#pragma unroll
    for (int g = 0; g < 4; ++g) {
      float v = bias_g[g];
#pragma unroll
      for (int w = 0; w < 4; ++w) v += scratch[(w * 4 + g) * 256 + lidx];
      g4[g] = v;
    }
    float i_s = 1.0f / (1.0f + expf(-g4[0]));
    float f_s = 1.0f / (1.0f + expf(-g4[1]));
    float g_t = tanhf(g4[2]);
    float o_s = 1.0f / (1.0f + expf(-g4[3]));
    c_state = f_s * c_state + i_s * g_t;
    float h = o_s * tanhf(c_state);

    unsigned short h_hi = f32_to_bf16_rn(h);
    unsigned short h_lo = f32_to_bf16_rn(h - bf16_to_f32(h_hi));
    size_t foff = ((((size_t)dir * 514 + (t + 1)) * 4 + bq) * 16 + kqh) * 64 + lane2;
    size_t eoff = foff * 8 + jrem;
    st_sc16(hf_hi + eoff, h_hi);
    st_sc16(hf_lo + eoff, h_lo);

    asm volatile("s_waitcnt vmcnt(0)" ::: "memory");
    __syncthreads();                 // all waves' write-through stores drained
    if (tid == 0) {
      __hip_atomic_fetch_add(&counters[dir * 32], 1u, __ATOMIC_RELAXED, __HIP_MEMORY_SCOPE_AGENT);
      unsigned int tgt = 128u * (unsigned)(s + 1);
      int guard = 0;
      while (__hip_atomic_load(&counters[dir * 32], __ATOMIC_RELAXED, __HIP_MEMORY_SCOPE_AGENT) < tgt
             && guard < 200000000) ++guard;
    }
    __syncthreads();
  }
}

// -------------------- emissions: feats = [h_f|h_b] @ W_h2t.T + b --------------------
__global__ __launch_bounds__(256) void feats_kernel(const unsigned short* __restrict__ hf_hi,
                                                    const unsigned short* __restrict__ hf_lo,
                                                    const unsigned short* __restrict__ w2t_hi,
                                                    const unsigned short* __restrict__ w2t_lo,
                                                    const float* __restrict__ b_h2t,
                                                    float* __restrict__ feats) {
  int t = blockIdx.x;
  int wave = threadIdx.x >> 6;       // = mt (batch tile)
  int lane = threadIdx.x & 63;
  f32x4 acc[2];
#pragma unroll
  for (int nt = 0; nt < 2; ++nt) { f32x4 z = {0.f, 0.f, 0.f, 0.f}; acc[nt] = z; }

  for (int kq = 0; kq < 32; ++kq) {
    int dir = kq >> 4, kqi = kq & 15;
    size_t af = (((((size_t)dir * 514 + (t + 1)) * 4 + wave) * 16 + kqi) * 64 + lane) * 8;
    short8 ah = *(const short8*)(hf_hi + af);
    short8 al = *(const short8*)(hf_lo + af);
#pragma unroll
    for (int nt = 0; nt < 2; ++nt) {
      size_t bf = (((size_t)nt * 32 + kq) * 64 + lane) * 8;
      short8 bh = *(const short8*)(w2t_hi + bf);
      short8 bl = *(const short8*)(w2t_lo + bf);
      acc[nt] = mfma16(ah, bh, acc[nt]);
      acc[nt] = mfma16(ah, bl, acc[nt]);
      acc[nt] = mfma16(al, bh, acc[nt]);
    }
  }
  int quad = lane >> 4, col = lane & 15;
#pragma unroll
  for (int nt = 0; nt < 2; ++nt) {
    int n = nt * 16 + col;
    if (n < NTAG) {
      float bb = b_h2t[n];
#pragma unroll
      for (int r = 0; r < 4; ++r) {
        int b = wave * 16 + quad * 4 + r;
        feats[((size_t)b * T_LEN + t) * 24 + n] = acc[nt][r] + bb;
      }
    }
  }
}

// -------------------- Viterbi (exact reference semantics) --------------------
__global__ __launch_bounds__(64) void viterbi_kernel(const float* __restrict__ feats,
                                                     const int* __restrict__ seq_len,
                                                     const float* __restrict__ trans,
                                                     unsigned char* __restrict__ bp,
                                                     float* __restrict__ out) {
  int b = blockIdx.x;
  int tid = threadIdx.x;
  __shared__ float tr[NTAG * NTAG];
  __shared__ float fv[NTAG];
  __shared__ float fvn[NTAG];
  for (int i = tid; i < NTAG * NTAG; i += 64) tr[i] = trans[i];
  if (tid < NTAG) fv[tid] = (tid == 1) ? 0.0f : NEGV;   // START = 1
  __syncthreads();
  int L = seq_len[b];
  for (int t = 0; t < T_LEN; ++t) {
    if (tid < NTAG) {
      float best = fv[0] + tr[tid * NTAG + 0];
      int arg = 0;
#pragma unroll 1
      for (int k = 1; k < NTAG; ++k) {
        float v = fv[k] + tr[tid * NTAG + k];
        if (v > best) { best = v; arg = k; }
      }
      bool active = (t < L);
      float ft = feats[((size_t)b * T_LEN + t) * 24 + tid];
      fvn[tid] = active ? (best + ft) : fv[tid];
      bp[((size_t)b * T_LEN + t) * 24 + tid] = (unsigned char)(active ? arg : tid);
    }
    __syncthreads();
    if (tid < NTAG) fv[tid] = fvn[tid];
    __syncthreads();
  }
  if (tid == 0) {
    float best = fv[0] + trans[2 * NTAG + 0];           // END = 2
    int arg = 0;
    for (int k = 1; k < NTAG; ++k) {
      float v = fv[k] + trans[2 * NTAG + k];
      if (v > best) { best = v; arg = k; }
    }
    out[b] = best;
    int tag = arg;
    out[64 + (size_t)b * T_LEN + (T_LEN - 1)] = (float)tag;
    for (int t = T_LEN - 2; t >= 0; --t) {
      tag = bp[((size_t)b * T_LEN + (t + 1)) * 24 + tag];
      out[64 + (size_t)b * T_LEN + t] = (float)tag;
    }
  }
}

// -------------------- launch --------------------
extern "C" void kernel_launch(void* const* d_in, const int* in_sizes, int n_in,
                              void* d_out, int out_size, void* d_ws, size_t ws_size,
                              hipStream_t stream) {
  const float* texts   = (const float*)d_in[0];
  const int*   seq_len = (const int*)d_in[1];
  const float* Wih_f   = (const float*)d_in[2];
  const float* Whh_f   = (const float*)d_in[3];
  const float* b_f     = (const float*)d_in[4];
  const float* Wih_b   = (const float*)d_in[5];
  const float* Whh_b   = (const float*)d_in[6];
  const float* b_b     = (const float*)d_in[7];
  const float* W_h2t   = (const float*)d_in[8];
  const float* b_h2t   = (const float*)d_in[9];
  const float* trans   = (const float*)d_in[10];
  (void)in_sizes; (void)n_in; (void)out_size; (void)ws_size;

  unsigned char* ws = (unsigned char*)d_ws;
  size_t off = 0;
  auto alloc = [&](size_t bytes) -> void* {
    void* p = ws + off;
    off += (bytes + 255) & ~(size_t)255;
    return p;
  };
  unsigned short* xf_hi  = (unsigned short*)alloc(33554432);
  unsigned short* xf_lo  = (unsigned short*)alloc(33554432);
  unsigned short* wf_hi  = (unsigned short*)alloc(8388608);
  unsigned short* wf_lo  = (unsigned short*)alloc(8388608);
  unsigned short* hf_hi  = (unsigned short*)alloc(67371008);   // 2*514*4096 frags *16B
  unsigned short* hf_lo  = (unsigned short*)alloc(67371008);
  unsigned short* w2t_hi = (unsigned short*)alloc(65536);
  unsigned short* w2t_lo = (unsigned short*)alloc(65536);
  float*          feats  = (float*)alloc(3145728);             // [64][512][24] f32
  unsigned char*  bp     = (unsigned char*)alloc(786432);      // [64][512][24] u8
  unsigned int*   ctrs   = (unsigned int*)alloc(256);

  // zero barrier counters and the h boundary slots (slot 0 and 513 per dir)
  hipMemsetAsync(ctrs, 0, 256, stream);
  for (int d = 0; d < 2; ++d) {
    hipMemsetAsync(hf_hi + ((size_t)d * 514 + 0)   * 32768, 0, 65536, stream);
    hipMemsetAsync(hf_hi + ((size_t)d * 514 + 513) * 32768, 0, 65536, stream);
    hipMemsetAsync(hf_lo + ((size_t)d * 514 + 0)   * 32768, 0, 65536, stream);
    hipMemsetAsync(hf_lo + ((size_t)d * 514 + 513) * 32768, 0, 65536, stream);
  }

  hipFuncSetAttribute((const void*)lstm_rec,
                      hipFuncAttributeMaxDynamicSharedMemorySize, 147456);

  prep_xf<<<8192, 256, 0, stream>>>(texts, xf_hi, xf_lo);
  prep_wf<<<2048, 256, 0, stream>>>(Whh_f, Wih_f, Whh_b, Wih_b, wf_hi, wf_lo);
  prep_w2t<<<16, 256, 0, stream>>>(W_h2t, w2t_hi, w2t_lo);
  lstm_rec<<<256, 256, 147456, stream>>>(xf_hi, xf_lo, wf_hi, wf_lo,
                                         b_f, b_b, hf_hi, hf_lo, ctrs);
  feats_kernel<<<512, 256, 0, stream>>>(hf_hi, hf_lo, w2t_hi, w2t_lo, b_h2t, feats);
  viterbi_kernel<<<64, 64, 0, stream>>>(feats, seq_len, trans, bp, (float*)d_out);
}

// Round 3
// 5050.448 us; speedup vs baseline: 1.9161x; 1.9161x over previous
//
#include <hip/hip_runtime.h>
#include <stdint.h>

#define T_LEN 512
#define BATCH 64
#define EMB   512
#define HID   512
#define NTAG  23
#define NEGV  -10000.0f

typedef __attribute__((ext_vector_type(4))) float f32x4;
typedef __attribute__((ext_vector_type(8))) short short8;

#define DEVI __device__ __forceinline__

DEVI unsigned short f32_to_bf16_rn(float f) {
  union { float f; uint32_t u; } v; v.f = f;
  uint32_t u = v.u;
  uint32_t r = u + 0x7FFFu + ((u >> 16) & 1u);
  return (unsigned short)(r >> 16);
}
DEVI float bf16_to_f32(unsigned short h) {
  union { float f; uint32_t u; } v; v.u = ((uint32_t)h) << 16;
  return v.f;
}

DEVI f32x4 mfma16(short8 a, short8 b, f32x4 c) {
  return __builtin_amdgcn_mfma_f32_16x16x32_bf16(a, b, c, 0, 0, 0);
}

// device-scope (LLC-coherent, cross-XCD) 16B load: sc1 bypasses the XCD L2,
// served by the Infinity Cache — NOT the HBM round trip sc0+sc1 forced in r1.
DEVI void ld_sc(const void* p, short8& d) {
  asm volatile("global_load_dwordx4 %0, %1, off sc1" : "=v"(d) : "v"(p) : "memory");
}
DEVI void wait_all(short8& a0, short8& a1, short8& a2, short8& a3,
                   short8& b0, short8& b1, short8& b2, short8& b3) {
  asm volatile("s_waitcnt vmcnt(0)"
               : "+v"(a0), "+v"(a1), "+v"(a2), "+v"(a3),
                 "+v"(b0), "+v"(b1), "+v"(b2), "+v"(b3)
               :: "memory");
}

// -------------------- fragment-layout packing kernels --------------------
// XF[t][mt4][kq16][lane64][8]  (A-frags of texts, hi/lo split)
__global__ __launch_bounds__(256) void prep_xf(const float* __restrict__ x,
                                               unsigned short* __restrict__ xf_hi,
                                               unsigned short* __restrict__ xf_lo) {
  int idx = blockIdx.x * 256 + threadIdx.x;       // 512*4*16*64 = 2097152
  int lane = idx & 63;
  int kq   = (idx >> 6) & 15;
  int mt   = (idx >> 10) & 3;
  int t    = idx >> 12;
  int b  = mt * 16 + (lane & 15);
  int e0 = kq * 32 + (lane >> 4) * 8;
  const float* src = x + ((size_t)b * T_LEN + t) * EMB + e0;
  size_t dst = (size_t)idx * 8;
#pragma unroll
  for (int i = 0; i < 8; ++i) {
    float v = src[i];
    unsigned short hi = f32_to_bf16_rn(v);
    unsigned short lo = f32_to_bf16_rn(v - bf16_to_f32(hi));
    xf_hi[dst + i] = hi;
    xf_lo[dst + i] = lo;
  }
}

// WF[dir2][mat2][js32][nt4][kq16][lane64][8]; mat0 = Whh, mat1 = Wih
__global__ __launch_bounds__(256) void prep_wf(const float* __restrict__ whh_f,
                                               const float* __restrict__ wih_f,
                                               const float* __restrict__ whh_b,
                                               const float* __restrict__ wih_b,
                                               unsigned short* __restrict__ wf_hi,
                                               unsigned short* __restrict__ wf_lo) {
  int idx = blockIdx.x * 256 + threadIdx.x;       // 2*2*32*4*16*64 = 524288
  int lane = idx & 63;
  int kq   = (idx >> 6) & 15;
  int nt   = (idx >> 10) & 3;
  int js   = (idx >> 12) & 31;
  int mat  = (idx >> 17) & 1;
  int dir  = (idx >> 18) & 1;
  const float* W = dir ? (mat ? wih_b : whh_b) : (mat ? wih_f : whh_f);
  int row = nt * 512 + js * 16 + (lane & 15);     // gate-major rows of [2048][512]
  int k0  = kq * 32 + (lane >> 4) * 8;
  const float* src = W + (size_t)row * 512 + k0;
  size_t dst = (size_t)idx * 8;
#pragma unroll
  for (int i = 0; i < 8; ++i) {
    float v = src[i];
    unsigned short hi = f32_to_bf16_rn(v);
    unsigned short lo = f32_to_bf16_rn(v - bf16_to_f32(hi));
    wf_hi[dst + i] = hi;
    wf_lo[dst + i] = lo;
  }
}

// W2T[nt2][kq32][lane64][8]  (B-frags of W_h2t [23][1024], N padded to 32)
__global__ __launch_bounds__(256) void prep_w2t(const float* __restrict__ w2t,
                                                unsigned short* __restrict__ o_hi,
                                                unsigned short* __restrict__ o_lo) {
  int idx = blockIdx.x * 256 + threadIdx.x;       // 2*32*64 = 4096
  int lane = idx & 63;
  int kq   = (idx >> 6) & 31;
  int nt   = (idx >> 11) & 1;
  int n  = nt * 16 + (lane & 15);
  int k0 = kq * 32 + (lane >> 4) * 8;
  size_t dst = (size_t)idx * 8;
#pragma unroll
  for (int i = 0; i < 8; ++i) {
    float v = (n < NTAG) ? w2t[(size_t)n * 1024 + k0 + i] : 0.0f;
    unsigned short hi = f32_to_bf16_rn(v);
    unsigned short lo = f32_to_bf16_rn(v - bf16_to_f32(hi));
    o_hi[dst + i] = hi;
    o_lo[dst + i] = lo;
  }
}

// -------------------- persistent BiLSTM recurrence --------------------
// Grid = 256 WGs, 1/CU. WG = (dir, js(16 j's), bq(16 batch rows)).
// HF[dir][slot 514][bq4][kq16][lane64][8] hi/lo; slot = t+1; slots 0,513 zeroed.
// Barrier: per-producer flag (64B stride), one relaxed agent fetch_add per WG
// per step; consumers ballot-poll the 32 producers of their (dir,bq) group.
__global__ __launch_bounds__(256, 1)
void lstm_rec(const unsigned short* __restrict__ xf_hi,
              const unsigned short* __restrict__ xf_lo,
              const unsigned short* __restrict__ wf_hi,
              const unsigned short* __restrict__ wf_lo,
              const float* __restrict__ bias_f,
              const float* __restrict__ bias_b,
              unsigned short* __restrict__ hf_hi,
              unsigned short* __restrict__ hf_lo,
              unsigned int* __restrict__ flags) {
  extern __shared__ unsigned char smem[];
  unsigned short* w_lds = (unsigned short*)smem;      // Whh_hi [0,64K) + Wih_hi [64K,128K)
  float* scratch = (float*)(smem + 131072);           // [wave4][nt4][lane64][4] = 16 KB

  int wg  = blockIdx.x;
  int dir = wg >> 7;
  int js  = (wg >> 2) & 31;
  int bq  = wg & 3;
  int tid  = threadIdx.x;
  int wave = tid >> 6;
  int lane = tid & 63;

  {
    const uint4* s0 = (const uint4*)wf_hi + ((size_t)(dir * 2 + 0) * 32 + js) * 4096;
    const uint4* s1 = (const uint4*)wf_hi + ((size_t)(dir * 2 + 1) * 32 + js) * 4096;
    uint4* d = (uint4*)w_lds;
    for (int i = tid; i < 4096; i += 256) { d[i] = s0[i]; d[4096 + i] = s1[i]; }
  }
  __syncthreads();

  int sm = tid >> 4;                 // local batch row 0..15
  int sj = tid & 15;                 // local j 0..15
  int jglob = js * 16 + sj;
  const float* bias = dir ? bias_b : bias_f;
  float bias_g[4];
#pragma unroll
  for (int g = 0; g < 4; ++g) bias_g[g] = bias[g * 512 + jglob];
  float c_state = 0.0f;

  // h write address pieces (constant per thread; see r1 derivation)
  int kqh   = jglob >> 5;
  int lane2 = ((jglob >> 3) & 3) * 16 + sm;
  int jrem  = jglob & 7;
  const unsigned int* grpflags = flags + (size_t)(dir * 4 + bq) * 32 * 16;
  unsigned int* myflag = flags + ((size_t)(dir * 4 + bq) * 32 + js) * 16;

  for (int s = 0; s < T_LEN; ++s) {
    int t = dir ? (T_LEN - 1 - s) : s;
    int rslot = dir ? (t + 2) : t;   // h[t+1] (bwd) / h[t-1] (fwd); zeros at s==0

    f32x4 acc[4];
#pragma unroll
    for (int nt = 0; nt < 4; ++nt) { f32x4 z = {0.f, 0.f, 0.f, 0.f}; acc[nt] = z; }

    // h-frag sc1 loads first (visible: end-of-previous-step barrier); their
    // ~600cyc LLC latency hides under the x-GEMM stream below.
    short8 hh[4], hl[4];
    {
      const short8* bh = (const short8*)hf_hi + ((((size_t)dir * 514 + rslot) * 4 + bq) * 16) * 64;
      const short8* bl = (const short8*)hf_lo + ((((size_t)dir * 514 + rslot) * 4 + bq) * 16) * 64;
#pragma unroll
      for (int q = 0; q < 4; ++q) {
        int kq = wave * 4 + q;
        ld_sc((const void*)(bh + kq * 64 + lane), hh[q]);
        ld_sc((const void*)(bl + kq * 64 + lane), hl[q]);
      }
    }

    // x-part GEMM (mat=1): Wih_hi from LDS, Wih_lo + xf streamed (L2-resident)
#pragma unroll
    for (int q = 0; q < 4; ++q) {
      int kq = wave * 4 + q;
      size_t xoff = ((((size_t)t * 4 + bq) * 16 + kq) * 64 + lane) * 8;
      short8 xh = *(const short8*)(xf_hi + xoff);
      short8 xl = *(const short8*)(xf_lo + xoff);
#pragma unroll
      for (int nt = 0; nt < 4; ++nt) {
        short8 bh = *(const short8*)&w_lds[((((size_t)(1 * 4 + nt)) * 16 + kq) * 64 + lane) * 8];
        short8 bl = *(const short8*)(wf_lo +
              ((((((size_t)dir * 2 + 1) * 32 + js) * 4 + nt) * 16 + kq) * 64 + lane) * 8);
        acc[nt] = mfma16(xh, bh, acc[nt]);
        acc[nt] = mfma16(xh, bl, acc[nt]);
        acc[nt] = mfma16(xl, bh, acc[nt]);
      }
    }

    wait_all(hh[0], hh[1], hh[2], hh[3], hl[0], hl[1], hl[2], hl[3]);

    // h-part GEMM (mat=0): Whh_hi from LDS, Whh_lo streamed
#pragma unroll
    for (int q = 0; q < 4; ++q) {
      int kq = wave * 4 + q;
#pragma unroll
      for (int nt = 0; nt < 4; ++nt) {
        short8 bh = *(const short8*)&w_lds[((((size_t)(0 * 4 + nt)) * 16 + kq) * 64 + lane) * 8];
        short8 bl = *(const short8*)(wf_lo +
              ((((((size_t)dir * 2 + 0) * 32 + js) * 4 + nt) * 16 + kq) * 64 + lane) * 8);
        acc[nt] = mfma16(hh[q], bh, acc[nt]);
        acc[nt] = mfma16(hh[q], bl, acc[nt]);
        acc[nt] = mfma16(hl[q], bh, acc[nt]);
      }
    }

    // cross-wave K-reduction via LDS
#pragma unroll
    for (int nt = 0; nt < 4; ++nt)
      *(f32x4*)&scratch[((size_t)(wave * 4 + nt) * 64 + lane) * 4] = acc[nt];
    __syncthreads();

    int lidx = (((sm >> 2) * 16) + sj) * 4 + (sm & 3);
    float g4[4];
#pragma unroll
    for (int g = 0; g < 4; ++g) {
      float v = bias_g[g];
#pragma unroll
      for (int w = 0; w < 4; ++w) v += scratch[(w * 4 + g) * 256 + lidx];
      g4[g] = v;
    }
    float i_s = 1.0f / (1.0f + expf(-g4[0]));
    float f_s = 1.0f / (1.0f + expf(-g4[1]));
    float g_t = tanhf(g4[2]);
    float o_s = 1.0f / (1.0f + expf(-g4[3]));
    c_state = f_s * c_state + i_s * g_t;
    float h = o_s * tanhf(c_state);

    // pack neighbor pairs (sj even/odd share a 4B word) and store u32 at
    // agent scope — same proven-coherent atomic family as the r1 barrier.
    unsigned int vhi = f32_to_bf16_rn(h);
    unsigned int vlo = f32_to_bf16_rn(h - bf16_to_f32((unsigned short)vhi));
    unsigned int phi = (unsigned int)__shfl_xor((int)vhi, 1);
    unsigned int plo = (unsigned int)__shfl_xor((int)vlo, 1);
    if ((sj & 1) == 0) {
      unsigned int whi = vhi | (phi << 16);
      unsigned int wlo = vlo | (plo << 16);
      size_t foff = ((((size_t)dir * 514 + (t + 1)) * 4 + bq) * 16 + kqh);
      size_t eoff = (foff * 64 + lane2) * 8 + jrem;     // even u16 index
      __hip_atomic_store((unsigned int*)(hf_hi + eoff), whi,
                         __ATOMIC_RELAXED, __HIP_MEMORY_SCOPE_AGENT);
      __hip_atomic_store((unsigned int*)(hf_lo + eoff), wlo,
                         __ATOMIC_RELAXED, __HIP_MEMORY_SCOPE_AGENT);
    }

    asm volatile("s_waitcnt vmcnt(0)" ::: "memory");   // h stores acked at LLC
    __syncthreads();                                   // => whole WG's stores are
    if (tid == 0)
      __hip_atomic_fetch_add(myflag, 1u, __ATOMIC_RELAXED, __HIP_MEMORY_SCOPE_AGENT);
    if (wave == 0) {
      unsigned tgt = (unsigned)(s + 1);
      const unsigned int* fp = grpflags + (size_t)(lane & 31) * 16;
      int guard = 0;
      for (;;) {
        unsigned v = tgt;
        if (lane < 32) v = __hip_atomic_load(fp, __ATOMIC_RELAXED, __HIP_MEMORY_SCOPE_AGENT);
        if (__ballot(v < tgt) == 0ull) break;
        if (++guard > 100000000) break;
      }
    }
    __syncthreads();
  }
}

// -------------------- emissions: feats = [h_f|h_b] @ W_h2t.T + b --------------------
__global__ __launch_bounds__(256) void feats_kernel(const unsigned short* __restrict__ hf_hi,
                                                    const unsigned short* __restrict__ hf_lo,
                                                    const unsigned short* __restrict__ w2t_hi,
                                                    const unsigned short* __restrict__ w2t_lo,
                                                    const float* __restrict__ b_h2t,
                                                    float* __restrict__ feats) {
  int t = blockIdx.x;
  int wave = threadIdx.x >> 6;       // = mt (batch tile)
  int lane = threadIdx.x & 63;
  f32x4 acc[2];
#pragma unroll
  for (int nt = 0; nt < 2; ++nt) { f32x4 z = {0.f, 0.f, 0.f, 0.f}; acc[nt] = z; }

  for (int kq = 0; kq < 32; ++kq) {
    int dir = kq >> 4, kqi = kq & 15;
    size_t af = (((((size_t)dir * 514 + (t + 1)) * 4 + wave) * 16 + kqi) * 64 + lane) * 8;
    short8 ah = *(const short8*)(hf_hi + af);
    short8 al = *(const short8*)(hf_lo + af);
#pragma unroll
    for (int nt = 0; nt < 2; ++nt) {
      size_t bf = (((size_t)nt * 32 + kq) * 64 + lane) * 8;
      short8 bh = *(const short8*)(w2t_hi + bf);
      short8 bl = *(const short8*)(w2t_lo + bf);
      acc[nt] = mfma16(ah, bh, acc[nt]);
      acc[nt] = mfma16(ah, bl, acc[nt]);
      acc[nt] = mfma16(al, bh, acc[nt]);
    }
  }
  int quad = lane >> 4, col = lane & 15;
#pragma unroll
  for (int nt = 0; nt < 2; ++nt) {
    int n = nt * 16 + col;
    if (n < NTAG) {
      float bb = b_h2t[n];
#pragma unroll
      for (int r = 0; r < 4; ++r) {
        int b = wave * 16 + quad * 4 + r;
        feats[((size_t)b * T_LEN + t) * 24 + n] = acc[nt][r] + bb;
      }
    }
  }
}

// -------------------- Viterbi (exact reference semantics, bp in LDS) --------------------
__global__ __launch_bounds__(64) void viterbi_kernel(const float* __restrict__ feats,
                                                     const int* __restrict__ seq_len,
                                                     const float* __restrict__ trans,
                                                     float* __restrict__ out) {
  int b = blockIdx.x;
  int tid = threadIdx.x;
  __shared__ float tr[NTAG * NTAG];
  __shared__ float fv[NTAG];
  __shared__ float fvn[NTAG];
  __shared__ unsigned char bp_s[T_LEN * 24];
  for (int i = tid; i < NTAG * NTAG; i += 64) tr[i] = trans[i];
  if (tid < NTAG) fv[tid] = (tid == 1) ? 0.0f : NEGV;   // START = 1
  __syncthreads();
  int L = seq_len[b];
  float ft = 0.0f;
  if (tid < NTAG) ft = feats[((size_t)b * T_LEN + 0) * 24 + tid];
  for (int t = 0; t < T_LEN; ++t) {
    float ftn = 0.0f;                 // prefetch next step's emissions early
    if (t + 1 < T_LEN && tid < NTAG) ftn = feats[((size_t)b * T_LEN + (t + 1)) * 24 + tid];
    if (tid < NTAG) {
      float best = fv[0] + tr[tid * NTAG + 0];
      int arg = 0;
#pragma unroll 1
      for (int k = 1; k < NTAG; ++k) {
        float v = fv[k] + tr[tid * NTAG + k];
        if (v > best) { best = v; arg = k; }
      }
      bool active = (t < L);
      fvn[tid] = active ? (best + ft) : fv[tid];
      bp_s[t * 24 + tid] = (unsigned char)(active ? arg : tid);
    }
    __syncthreads();
    if (tid < NTAG) fv[tid] = fvn[tid];
    __syncthreads();
    ft = ftn;
  }
  if (tid == 0) {
    float best = fv[0] + trans[2 * NTAG + 0];           // END = 2
    int arg = 0;
    for (int k = 1; k < NTAG; ++k) {
      float v = fv[k] + trans[2 * NTAG + k];
      if (v > best) { best = v; arg = k; }
    }
    out[b] = best;
    int tag = arg;
    out[64 + (size_t)b * T_LEN + (T_LEN - 1)] = (float)tag;
    for (int t = T_LEN - 2; t >= 0; --t) {
      tag = bp_s[(t + 1) * 24 + tag];
      out[64 + (size_t)b * T_LEN + t] = (float)tag;
    }
  }
}

// -------------------- launch --------------------
extern "C" void kernel_launch(void* const* d_in, const int* in_sizes, int n_in,
                              void* d_out, int out_size, void* d_ws, size_t ws_size,
                              hipStream_t stream) {
  const float* texts   = (const float*)d_in[0];
  const int*   seq_len = (const int*)d_in[1];
  const float* Wih_f   = (const float*)d_in[2];
  const float* Whh_f   = (const float*)d_in[3];
  const float* b_f     = (const float*)d_in[4];
  const float* Wih_b   = (const float*)d_in[5];
  const float* Whh_b   = (const float*)d_in[6];
  const float* b_b     = (const float*)d_in[7];
  const float* W_h2t   = (const float*)d_in[8];
  const float* b_h2t   = (const float*)d_in[9];
  const float* trans   = (const float*)d_in[10];
  (void)in_sizes; (void)n_in; (void)out_size; (void)ws_size;

  unsigned char* ws = (unsigned char*)d_ws;
  size_t off = 0;
  auto alloc = [&](size_t bytes) -> void* {
    void* p = ws + off;
    off += (bytes + 255) & ~(size_t)255;
    return p;
  };
  // total ~218.4 MB — within the proven r1 budget (no 536 MB xg buffer!)
  unsigned short* xf_hi  = (unsigned short*)alloc(33554432);
  unsigned short* xf_lo  = (unsigned short*)alloc(33554432);
  unsigned short* wf_hi  = (unsigned short*)alloc(8388608);
  unsigned short* wf_lo  = (unsigned short*)alloc(8388608);
  unsigned short* hf_hi  = (unsigned short*)alloc(67371008);   // 2*514*4096 frags *16B
  unsigned short* hf_lo  = (unsigned short*)alloc(67371008);
  unsigned short* w2t_hi = (unsigned short*)alloc(65536);
  unsigned short* w2t_lo = (unsigned short*)alloc(65536);
  float*          feats  = (float*)alloc(3145728);             // [64][512][24] f32
  unsigned int*   flags  = (unsigned int*)alloc(16384);        // [2][4][32] @64B stride

  // zero flags and the h boundary slots (slot 0 and 513 per dir)
  hipMemsetAsync(flags, 0, 16384, stream);
  for (int d = 0; d < 2; ++d) {
    hipMemsetAsync(hf_hi + ((size_t)d * 514 + 0)   * 32768, 0, 65536, stream);
    hipMemsetAsync(hf_hi + ((size_t)d * 514 + 513) * 32768, 0, 65536, stream);
    hipMemsetAsync(hf_lo + ((size_t)d * 514 + 0)   * 32768, 0, 65536, stream);
    hipMemsetAsync(hf_lo + ((size_t)d * 514 + 513) * 32768, 0, 65536, stream);
  }

  hipFuncSetAttribute((const void*)lstm_rec,
                      hipFuncAttributeMaxDynamicSharedMemorySize, 147456);

  prep_xf<<<8192, 256, 0, stream>>>(texts, xf_hi, xf_lo);
  prep_wf<<<2048, 256, 0, stream>>>(Whh_f, Wih_f, Whh_b, Wih_b, wf_hi, wf_lo);
  prep_w2t<<<16, 256, 0, stream>>>(W_h2t, w2t_hi, w2t_lo);
  lstm_rec<<<256, 256, 147456, stream>>>(xf_hi, xf_lo, wf_hi, wf_lo,
                                         b_f, b_b, hf_hi, hf_lo, flags);
  feats_kernel<<<512, 256, 0, stream>>>(hf_hi, hf_lo, w2t_hi, w2t_lo, b_h2t, feats);
  viterbi_kernel<<<64, 64, 0, stream>>>(feats, seq_len, trans, (float*)d_out);
}

// Round 4
// 3323.181 us; speedup vs baseline: 2.9120x; 1.5198x over previous
//
#include <hip/hip_runtime.h>
#include <stdint.h>

#define T_LEN 512
#define BATCH 64
#define EMB   512
#define HID   512
#define NTAG  23
#define NEGV  -10000.0f

typedef __attribute__((ext_vector_type(4))) float f32x4;
typedef __attribute__((ext_vector_type(8))) short short8;

#define DEVI __device__ __forceinline__

DEVI unsigned short f32_to_bf16_rn(float f) {
  union { float f; uint32_t u; } v; v.f = f;
  uint32_t u = v.u;
  uint32_t r = u + 0x7FFFu + ((u >> 16) & 1u);
  return (unsigned short)(r >> 16);
}
DEVI float bf16_to_f32(unsigned short h) {
  union { float f; uint32_t u; } v; v.u = ((uint32_t)h) << 16;
  return v.f;
}

DEVI f32x4 mfma16(short8 a, short8 b, f32x4 c) {
  return __builtin_amdgcn_mfma_f32_16x16x32_bf16(a, b, c, 0, 0, 0);
}

// device-scope (LLC-coherent, cross-XCD) 16B load: sc1 bypasses the XCD L2,
// served by the Infinity Cache.
DEVI void ld_sc(const void* p, short8& d) {
  asm volatile("global_load_dwordx4 %0, %1, off sc1" : "=v"(d) : "v"(p) : "memory");
}
DEVI void wait_all(short8& a0, short8& a1, short8& a2, short8& a3,
                   short8& b0, short8& b1, short8& b2, short8& b3) {
  asm volatile("s_waitcnt vmcnt(0)"
               : "+v"(a0), "+v"(a1), "+v"(a2), "+v"(a3),
                 "+v"(b0), "+v"(b1), "+v"(b2), "+v"(b3)
               :: "memory");
}

// -------------------- fragment-layout packing kernels --------------------
// XF[t][mt4][kq16][lane64][8]  (A-frags of texts, hi/lo split)
__global__ __launch_bounds__(256) void prep_xf(const float* __restrict__ x,
                                               unsigned short* __restrict__ xf_hi,
                                               unsigned short* __restrict__ xf_lo) {
  int idx = blockIdx.x * 256 + threadIdx.x;       // 512*4*16*64 = 2097152
  int lane = idx & 63;
  int kq   = (idx >> 6) & 15;
  int mt   = (idx >> 10) & 3;
  int t    = idx >> 12;
  int b  = mt * 16 + (lane & 15);
  int e0 = kq * 32 + (lane >> 4) * 8;
  const float* src = x + ((size_t)b * T_LEN + t) * EMB + e0;
  size_t dst = (size_t)idx * 8;
#pragma unroll
  for (int i = 0; i < 8; ++i) {
    float v = src[i];
    unsigned short hi = f32_to_bf16_rn(v);
    unsigned short lo = f32_to_bf16_rn(v - bf16_to_f32(hi));
    xf_hi[dst + i] = hi;
    xf_lo[dst + i] = lo;
  }
}

// WF[dir2][mat2][js32][nt4][kq16][lane64][8]; mat0 = Whh, mat1 = Wih
__global__ __launch_bounds__(256) void prep_wf(const float* __restrict__ whh_f,
                                               const float* __restrict__ wih_f,
                                               const float* __restrict__ whh_b,
                                               const float* __restrict__ wih_b,
                                               unsigned short* __restrict__ wf_hi,
                                               unsigned short* __restrict__ wf_lo) {
  int idx = blockIdx.x * 256 + threadIdx.x;       // 2*2*32*4*16*64 = 524288
  int lane = idx & 63;
  int kq   = (idx >> 6) & 15;
  int nt   = (idx >> 10) & 3;
  int js   = (idx >> 12) & 31;
  int mat  = (idx >> 17) & 1;
  int dir  = (idx >> 18) & 1;
  const float* W = dir ? (mat ? wih_b : whh_b) : (mat ? wih_f : whh_f);
  int row = nt * 512 + js * 16 + (lane & 15);     // gate-major rows of [2048][512]
  int k0  = kq * 32 + (lane >> 4) * 8;
  const float* src = W + (size_t)row * 512 + k0;
  size_t dst = (size_t)idx * 8;
#pragma unroll
  for (int i = 0; i < 8; ++i) {
    float v = src[i];
    unsigned short hi = f32_to_bf16_rn(v);
    unsigned short lo = f32_to_bf16_rn(v - bf16_to_f32(hi));
    wf_hi[dst + i] = hi;
    wf_lo[dst + i] = lo;
  }
}

// W2T[nt2][kq32][lane64][8]  (B-frags of W_h2t [23][1024], N padded to 32)
__global__ __launch_bounds__(256) void prep_w2t(const float* __restrict__ w2t,
                                                unsigned short* __restrict__ o_hi,
                                                unsigned short* __restrict__ o_lo) {
  int idx = blockIdx.x * 256 + threadIdx.x;       // 2*32*64 = 4096
  int lane = idx & 63;
  int kq   = (idx >> 6) & 31;
  int nt   = (idx >> 11) & 1;
  int n  = nt * 16 + (lane & 15);
  int k0 = kq * 32 + (lane >> 4) * 8;
  size_t dst = (size_t)idx * 8;
#pragma unroll
  for (int i = 0; i < 8; ++i) {
    float v = (n < NTAG) ? w2t[(size_t)n * 1024 + k0 + i] : 0.0f;
    unsigned short hi = f32_to_bf16_rn(v);
    unsigned short lo = f32_to_bf16_rn(v - bf16_to_f32(hi));
    o_hi[dst + i] = hi;
    o_lo[dst + i] = lo;
  }
}

// -------------------- persistent BiLSTM recurrence --------------------
// Grid = 256 WGs, 1/CU. WG = (dir, js(16 j's), bq(16 batch rows)).
// HF[dir][slot 514][bq4][kq16][lane64][8] hi/lo; slot = t+1; slots 0,513 zeroed.
// r4: hi-weights in LDS (unchanged), lo-weights PRELOADED INTO REGISTERS
// (step-invariant: 32 short8 = 128 VGPRs/thread; at 256 thr/WG, 1 WG/CU we
// have 1 wave/SIMD -> ~512 VGPR budget). Per-step L2 streaming drops from
// 160 KB to 32 KB (xf only); serial-path jitter shrinks accordingly.
__global__ __launch_bounds__(256, 1)
void lstm_rec(const unsigned short* __restrict__ xf_hi,
              const unsigned short* __restrict__ xf_lo,
              const unsigned short* __restrict__ wf_hi,
              const unsigned short* __restrict__ wf_lo,
              const float* __restrict__ bias_f,
              const float* __restrict__ bias_b,
              unsigned short* __restrict__ hf_hi,
              unsigned short* __restrict__ hf_lo,
              unsigned int* __restrict__ flags) {
  extern __shared__ unsigned char smem[];
  unsigned short* w_lds = (unsigned short*)smem;      // Whh_hi [0,64K) + Wih_hi [64K,128K)
  float* scratch = (float*)(smem + 131072);           // [wave4][nt4][lane64][4] = 16 KB

  int wg  = blockIdx.x;
  int dir = wg >> 7;
  int js  = (wg >> 2) & 31;
  int bq  = wg & 3;
  int tid  = threadIdx.x;
  int wave = tid >> 6;
  int lane = tid & 63;

  {
    const uint4* s0 = (const uint4*)wf_hi + ((size_t)(dir * 2 + 0) * 32 + js) * 4096;
    const uint4* s1 = (const uint4*)wf_hi + ((size_t)(dir * 2 + 1) * 32 + js) * 4096;
    uint4* d = (uint4*)w_lds;
    for (int i = tid; i < 4096; i += 256) { d[i] = s0[i]; d[4096 + i] = s1[i]; }
  }

  // preload step-invariant lo-weight fragments into registers (this wave's
  // kq slice: 4 kq x 4 nt x 2 matrices = 32 short8 = 128 VGPRs)
  short8 wlo_h[4][4], wlo_x[4][4];
#pragma unroll
  for (int q = 0; q < 4; ++q) {
    int kq = wave * 4 + q;
#pragma unroll
    for (int nt = 0; nt < 4; ++nt) {
      wlo_h[q][nt] = *(const short8*)(wf_lo +
            ((((((size_t)dir * 2 + 0) * 32 + js) * 4 + nt) * 16 + kq) * 64 + lane) * 8);
      wlo_x[q][nt] = *(const short8*)(wf_lo +
            ((((((size_t)dir * 2 + 1) * 32 + js) * 4 + nt) * 16 + kq) * 64 + lane) * 8);
    }
  }
  __syncthreads();

  int sm = tid >> 4;                 // local batch row 0..15
  int sj = tid & 15;                 // local j 0..15
  int jglob = js * 16 + sj;
  const float* bias = dir ? bias_b : bias_f;
  float bias_g[4];
#pragma unroll
  for (int g = 0; g < 4; ++g) bias_g[g] = bias[g * 512 + jglob];
  float c_state = 0.0f;

  // h write address pieces (constant per thread)
  int kqh   = jglob >> 5;
  int lane2 = ((jglob >> 3) & 3) * 16 + sm;
  int jrem  = jglob & 7;
  const unsigned int* grpflags = flags + (size_t)(dir * 4 + bq) * 32 * 16;
  unsigned int* myflag = flags + ((size_t)(dir * 4 + bq) * 32 + js) * 16;

  for (int s = 0; s < T_LEN; ++s) {
    int t = dir ? (T_LEN - 1 - s) : s;
    int rslot = dir ? (t + 2) : t;   // h[t+1] (bwd) / h[t-1] (fwd); zeros at s==0

    f32x4 acc[4];
#pragma unroll
    for (int nt = 0; nt < 4; ++nt) { f32x4 z = {0.f, 0.f, 0.f, 0.f}; acc[nt] = z; }

    // h-frag sc1 loads first (made visible by the end-of-previous-step
    // barrier); latency hides under the x-GEMM below.
    short8 hh[4], hl[4];
    {
      const short8* bh = (const short8*)hf_hi + ((((size_t)dir * 514 + rslot) * 4 + bq) * 16) * 64;
      const short8* bl = (const short8*)hf_lo + ((((size_t)dir * 514 + rslot) * 4 + bq) * 16) * 64;
#pragma unroll
      for (int q = 0; q < 4; ++q) {
        int kq = wave * 4 + q;
        ld_sc((const void*)(bh + kq * 64 + lane), hh[q]);
        ld_sc((const void*)(bl + kq * 64 + lane), hl[q]);
      }
    }

    // x-part GEMM (mat=1): Wih_hi from LDS, Wih_lo from registers,
    // xf streamed (only remaining per-step L2 stream: 32 KB/WG)
#pragma unroll
    for (int q = 0; q < 4; ++q) {
      int kq = wave * 4 + q;
      size_t xoff = ((((size_t)t * 4 + bq) * 16 + kq) * 64 + lane) * 8;
      short8 xh = *(const short8*)(xf_hi + xoff);
      short8 xl = *(const short8*)(xf_lo + xoff);
#pragma unroll
      for (int nt = 0; nt < 4; ++nt) {
        short8 bh = *(const short8*)&w_lds[((((size_t)(1 * 4 + nt)) * 16 + kq) * 64 + lane) * 8];
        acc[nt] = mfma16(xh, bh, acc[nt]);
        acc[nt] = mfma16(xh, wlo_x[q][nt], acc[nt]);
        acc[nt] = mfma16(xl, bh, acc[nt]);
      }
    }

    wait_all(hh[0], hh[1], hh[2], hh[3], hl[0], hl[1], hl[2], hl[3]);

    // h-part GEMM (mat=0): Whh_hi from LDS, Whh_lo from registers
#pragma unroll
    for (int q = 0; q < 4; ++q) {
      int kq = wave * 4 + q;
#pragma unroll
      for (int nt = 0; nt < 4; ++nt) {
        short8 bh = *(const short8*)&w_lds[((((size_t)(0 * 4 + nt)) * 16 + kq) * 64 + lane) * 8];
        acc[nt] = mfma16(hh[q], bh, acc[nt]);
        acc[nt] = mfma16(hh[q], wlo_h[q][nt], acc[nt]);
        acc[nt] = mfma16(hl[q], bh, acc[nt]);
      }
    }

    // cross-wave K-reduction via LDS
#pragma unroll
    for (int nt = 0; nt < 4; ++nt)
      *(f32x4*)&scratch[((size_t)(wave * 4 + nt) * 64 + lane) * 4] = acc[nt];
    __syncthreads();

    int lidx = (((sm >> 2) * 16) + sj) * 4 + (sm & 3);
    float g4[4];
#pragma unroll
    for (int g = 0; g < 4; ++g) {
      float v = bias_g[g];
#pragma unroll
      for (int w = 0; w < 4; ++w) v += scratch[(w * 4 + g) * 256 + lidx];
      g4[g] = v;
    }
    float i_s = 1.0f / (1.0f + expf(-g4[0]));
    float f_s = 1.0f / (1.0f + expf(-g4[1]));
    float g_t = tanhf(g4[2]);
    float o_s = 1.0f / (1.0f + expf(-g4[3]));
    c_state = f_s * c_state + i_s * g_t;
    float h = o_s * tanhf(c_state);

    // pack neighbor pairs (sj even/odd share a 4B word), agent-scope u32 store
    unsigned int vhi = f32_to_bf16_rn(h);
    unsigned int vlo = f32_to_bf16_rn(h - bf16_to_f32((unsigned short)vhi));
    unsigned int phi = (unsigned int)__shfl_xor((int)vhi, 1);
    unsigned int plo = (unsigned int)__shfl_xor((int)vlo, 1);
    if ((sj & 1) == 0) {
      unsigned int whi = vhi | (phi << 16);
      unsigned int wlo = vlo | (plo << 16);
      size_t foff = ((((size_t)dir * 514 + (t + 1)) * 4 + bq) * 16 + kqh);
      size_t eoff = (foff * 64 + lane2) * 8 + jrem;     // even u16 index
      __hip_atomic_store((unsigned int*)(hf_hi + eoff), whi,
                         __ATOMIC_RELAXED, __HIP_MEMORY_SCOPE_AGENT);
      __hip_atomic_store((unsigned int*)(hf_lo + eoff), wlo,
                         __ATOMIC_RELAXED, __HIP_MEMORY_SCOPE_AGENT);
    }

    asm volatile("s_waitcnt vmcnt(0)" ::: "memory");   // h stores acked at LLC
    __syncthreads();                                   // => whole WG's stores are
    if (tid == 0)
      __hip_atomic_fetch_add(myflag, 1u, __ATOMIC_RELAXED, __HIP_MEMORY_SCOPE_AGENT);
    if (wave == 0) {
      unsigned tgt = (unsigned)(s + 1);
      const unsigned int* fp = grpflags + (size_t)(lane & 31) * 16;
      int guard = 0;
      for (;;) {
        unsigned v = tgt;
        if (lane < 32) v = __hip_atomic_load(fp, __ATOMIC_RELAXED, __HIP_MEMORY_SCOPE_AGENT);
        if (__ballot(v < tgt) == 0ull) break;
        if (++guard > 100000000) break;
      }
    }
    __syncthreads();
  }
}

// -------------------- emissions: feats = [h_f|h_b] @ W_h2t.T + b --------------------
__global__ __launch_bounds__(256) void feats_kernel(const unsigned short* __restrict__ hf_hi,
                                                    const unsigned short* __restrict__ hf_lo,
                                                    const unsigned short* __restrict__ w2t_hi,
                                                    const unsigned short* __restrict__ w2t_lo,
                                                    const float* __restrict__ b_h2t,
                                                    float* __restrict__ feats) {
  int t = blockIdx.x;
  int wave = threadIdx.x >> 6;       // = mt (batch tile)
  int lane = threadIdx.x & 63;
  f32x4 acc[2];
#pragma unroll
  for (int nt = 0; nt < 2; ++nt) { f32x4 z = {0.f, 0.f, 0.f, 0.f}; acc[nt] = z; }

  for (int kq = 0; kq < 32; ++kq) {
    int dir = kq >> 4, kqi = kq & 15;
    size_t af = (((((size_t)dir * 514 + (t + 1)) * 4 + wave) * 16 + kqi) * 64 + lane) * 8;
    short8 ah = *(const short8*)(hf_hi + af);
    short8 al = *(const short8*)(hf_lo + af);
#pragma unroll
    for (int nt = 0; nt < 2; ++nt) {
      size_t bf = (((size_t)nt * 32 + kq) * 64 + lane) * 8;
      short8 bh = *(const short8*)(w2t_hi + bf);
      short8 bl = *(const short8*)(w2t_lo + bf);
      acc[nt] = mfma16(ah, bh, acc[nt]);
      acc[nt] = mfma16(ah, bl, acc[nt]);
      acc[nt] = mfma16(al, bh, acc[nt]);
    }
  }
  int quad = lane >> 4, col = lane & 15;
#pragma unroll
  for (int nt = 0; nt < 2; ++nt) {
    int n = nt * 16 + col;
    if (n < NTAG) {
      float bb = b_h2t[n];
#pragma unroll
      for (int r = 0; r < 4; ++r) {
        int b = wave * 16 + quad * 4 + r;
        feats[((size_t)b * T_LEN + t) * 24 + n] = acc[nt][r] + bb;
      }
    }
  }
}

// -------------------- Viterbi (exact reference semantics, bp in LDS) --------------------
__global__ __launch_bounds__(64) void viterbi_kernel(const float* __restrict__ feats,
                                                     const int* __restrict__ seq_len,
                                                     const float* __restrict__ trans,
                                                     float* __restrict__ out) {
  int b = blockIdx.x;
  int tid = threadIdx.x;
  __shared__ float tr[NTAG * NTAG];
  __shared__ float fv[NTAG];
  __shared__ float fvn[NTAG];
  __shared__ unsigned char bp_s[T_LEN * 24];
  for (int i = tid; i < NTAG * NTAG; i += 64) tr[i] = trans[i];
  if (tid < NTAG) fv[tid] = (tid == 1) ? 0.0f : NEGV;   // START = 1
  __syncthreads();
  int L = seq_len[b];
  float ft = 0.0f;
  if (tid < NTAG) ft = feats[((size_t)b * T_LEN + 0) * 24 + tid];
  for (int t = 0; t < T_LEN; ++t) {
    float ftn = 0.0f;                 // prefetch next step's emissions early
    if (t + 1 < T_LEN && tid < NTAG) ftn = feats[((size_t)b * T_LEN + (t + 1)) * 24 + tid];
    if (tid < NTAG) {
      float best = fv[0] + tr[tid * NTAG + 0];
      int arg = 0;
#pragma unroll 1
      for (int k = 1; k < NTAG; ++k) {
        float v = fv[k] + tr[tid * NTAG + k];
        if (v > best) { best = v; arg = k; }
      }
      bool active = (t < L);
      fvn[tid] = active ? (best + ft) : fv[tid];
      bp_s[t * 24 + tid] = (unsigned char)(active ? arg : tid);
    }
    __syncthreads();
    if (tid < NTAG) fv[tid] = fvn[tid];
    __syncthreads();
    ft = ftn;
  }
  if (tid == 0) {
    float best = fv[0] + trans[2 * NTAG + 0];           // END = 2
    int arg = 0;
    for (int k = 1; k < NTAG; ++k) {
      float v = fv[k] + trans[2 * NTAG + k];
      if (v > best) { best = v; arg = k; }
    }
    out[b] = best;
    int tag = arg;
    out[64 + (size_t)b * T_LEN + (T_LEN - 1)] = (float)tag;
    for (int t = T_LEN - 2; t >= 0; --t) {
      tag = bp_s[(t + 1) * 24 + tag];
      out[64 + (size_t)b * T_LEN + t] = (float)tag;
    }
  }
}

// -------------------- launch --------------------
extern "C" void kernel_launch(void* const* d_in, const int* in_sizes, int n_in,
                              void* d_out, int out_size, void* d_ws, size_t ws_size,
                              hipStream_t stream) {
  const float* texts   = (const float*)d_in[0];
  const int*   seq_len = (const int*)d_in[1];
  const float* Wih_f   = (const float*)d_in[2];
  const float* Whh_f   = (const float*)d_in[3];
  const float* b_f     = (const float*)d_in[4];
  const float* Wih_b   = (const float*)d_in[5];
  const float* Whh_b   = (const float*)d_in[6];
  const float* b_b     = (const float*)d_in[7];
  const float* W_h2t   = (const float*)d_in[8];
  const float* b_h2t   = (const float*)d_in[9];
  const float* trans   = (const float*)d_in[10];
  (void)in_sizes; (void)n_in; (void)out_size; (void)ws_size;

  unsigned char* ws = (unsigned char*)d_ws;
  size_t off = 0;
  auto alloc = [&](size_t bytes) -> void* {
    void* p = ws + off;
    off += (bytes + 255) & ~(size_t)255;
    return p;
  };
  // total ~218.4 MB — within the proven budget
  unsigned short* xf_hi  = (unsigned short*)alloc(33554432);
  unsigned short* xf_lo  = (unsigned short*)alloc(33554432);
  unsigned short* wf_hi  = (unsigned short*)alloc(8388608);
  unsigned short* wf_lo  = (unsigned short*)alloc(8388608);
  unsigned short* hf_hi  = (unsigned short*)alloc(67371008);   // 2*514*4096 frags *16B
  unsigned short* hf_lo  = (unsigned short*)alloc(67371008);
  unsigned short* w2t_hi = (unsigned short*)alloc(65536);
  unsigned short* w2t_lo = (unsigned short*)alloc(65536);
  float*          feats  = (float*)alloc(3145728);             // [64][512][24] f32
  unsigned int*   flags  = (unsigned int*)alloc(16384);        // [2][4][32] @64B stride

  // zero flags and the h boundary slots (slot 0 and 513 per dir)
  hipMemsetAsync(flags, 0, 16384, stream);
  for (int d = 0; d < 2; ++d) {
    hipMemsetAsync(hf_hi + ((size_t)d * 514 + 0)   * 32768, 0, 65536, stream);
    hipMemsetAsync(hf_hi + ((size_t)d * 514 + 513) * 32768, 0, 65536, stream);
    hipMemsetAsync(hf_lo + ((size_t)d * 514 + 0)   * 32768, 0, 65536, stream);
    hipMemsetAsync(hf_lo + ((size_t)d * 514 + 513) * 32768, 0, 65536, stream);
  }

  hipFuncSetAttribute((const void*)lstm_rec,
                      hipFuncAttributeMaxDynamicSharedMemorySize, 147456);

  prep_xf<<<8192, 256, 0, stream>>>(texts, xf_hi, xf_lo);
  prep_wf<<<2048, 256, 0, stream>>>(Whh_f, Wih_f, Whh_b, Wih_b, wf_hi, wf_lo);
  prep_w2t<<<16, 256, 0, stream>>>(W_h2t, w2t_hi, w2t_lo);
  lstm_rec<<<256, 256, 147456, stream>>>(xf_hi, xf_lo, wf_hi, wf_lo,
                                         b_f, b_b, hf_hi, hf_lo, flags);
  feats_kernel<<<512, 256, 0, stream>>>(hf_hi, hf_lo, w2t_hi, w2t_lo, b_h2t, feats);
  viterbi_kernel<<<64, 64, 0, stream>>>(feats, seq_len, trans, (float*)d_out);
}

// Round 5
// 2908.305 us; speedup vs baseline: 3.3274x; 1.1427x over previous
//
#include <hip/hip_runtime.h>
#include <stdint.h>

#define T_LEN 512
#define BATCH 64
#define EMB   512
#define HID   512
#define NTAG  23
#define NEGV  -10000.0f

typedef __attribute__((ext_vector_type(4))) float f32x4;
typedef __attribute__((ext_vector_type(8))) short short8;

#define DEVI __device__ __forceinline__

DEVI unsigned short f32_to_bf16_rn(float f) {
  union { float f; uint32_t u; } v; v.f = f;
  uint32_t u = v.u;
  uint32_t r = u + 0x7FFFu + ((u >> 16) & 1u);
  return (unsigned short)(r >> 16);
}
DEVI float bf16_to_f32(unsigned short h) {
  union { float f; uint32_t u; } v; v.u = ((uint32_t)h) << 16;
  return v.f;
}

DEVI f32x4 mfma16(short8 a, short8 b, f32x4 c) {
  return __builtin_amdgcn_mfma_f32_16x16x32_bf16(a, b, c, 0, 0, 0);
}

// device-scope (LLC-coherent, cross-XCD) 16B load: sc1 bypasses the XCD L2,
// served by the Infinity Cache.
DEVI void ld_sc(const void* p, short8& d) {
  asm volatile("global_load_dwordx4 %0, %1, off sc1" : "=v"(d) : "v"(p) : "memory");
}
DEVI void wait_all(short8& a0, short8& a1, short8& a2, short8& a3,
                   short8& b0, short8& b1, short8& b2, short8& b3) {
  asm volatile("s_waitcnt vmcnt(0)"
               : "+v"(a0), "+v"(a1), "+v"(a2), "+v"(a3),
                 "+v"(b0), "+v"(b1), "+v"(b2), "+v"(b3)
               :: "memory");
}

// -------------------- fragment-layout packing kernels --------------------
// XF[t][mt4][kq16][lane64][8]  (A-frags of texts, hi/lo split)
__global__ __launch_bounds__(256) void prep_xf(const float* __restrict__ x,
                                               unsigned short* __restrict__ xf_hi,
                                               unsigned short* __restrict__ xf_lo) {
  int idx = blockIdx.x * 256 + threadIdx.x;       // 512*4*16*64 = 2097152
  int lane = idx & 63;
  int kq   = (idx >> 6) & 15;
  int mt   = (idx >> 10) & 3;
  int t    = idx >> 12;
  int b  = mt * 16 + (lane & 15);
  int e0 = kq * 32 + (lane >> 4) * 8;
  const float* src = x + ((size_t)b * T_LEN + t) * EMB + e0;
  size_t dst = (size_t)idx * 8;
#pragma unroll
  for (int i = 0; i < 8; ++i) {
    float v = src[i];
    unsigned short hi = f32_to_bf16_rn(v);
    unsigned short lo = f32_to_bf16_rn(v - bf16_to_f32(hi));
    xf_hi[dst + i] = hi;
    xf_lo[dst + i] = lo;
  }
}

// WF[dir2][mat2][js32][nt4][kq16][lane64][8]; mat0 = Whh, mat1 = Wih
__global__ __launch_bounds__(256) void prep_wf(const float* __restrict__ whh_f,
                                               const float* __restrict__ wih_f,
                                               const float* __restrict__ whh_b,
                                               const float* __restrict__ wih_b,
                                               unsigned short* __restrict__ wf_hi,
                                               unsigned short* __restrict__ wf_lo) {
  int idx = blockIdx.x * 256 + threadIdx.x;       // 2*2*32*4*16*64 = 524288
  int lane = idx & 63;
  int kq   = (idx >> 6) & 15;
  int nt   = (idx >> 10) & 3;
  int js   = (idx >> 12) & 31;
  int mat  = (idx >> 17) & 1;
  int dir  = (idx >> 18) & 1;
  const float* W = dir ? (mat ? wih_b : whh_b) : (mat ? wih_f : whh_f);
  int row = nt * 512 + js * 16 + (lane & 15);     // gate-major rows of [2048][512]
  int k0  = kq * 32 + (lane >> 4) * 8;
  const float* src = W + (size_t)row * 512 + k0;
  size_t dst = (size_t)idx * 8;
#pragma unroll
  for (int i = 0; i < 8; ++i) {
    float v = src[i];
    unsigned short hi = f32_to_bf16_rn(v);
    unsigned short lo = f32_to_bf16_rn(v - bf16_to_f32(hi));
    wf_hi[dst + i] = hi;
    wf_lo[dst + i] = lo;
  }
}

// W2T[nt2][kq32][lane64][8]  (B-frags of W_h2t [23][1024], N padded to 32)
__global__ __launch_bounds__(256) void prep_w2t(const float* __restrict__ w2t,
                                                unsigned short* __restrict__ o_hi,
                                                unsigned short* __restrict__ o_lo) {
  int idx = blockIdx.x * 256 + threadIdx.x;       // 2*32*64 = 4096
  int lane = idx & 63;
  int kq   = (idx >> 6) & 31;
  int nt   = (idx >> 11) & 1;
  int n  = nt * 16 + (lane & 15);
  int k0 = kq * 32 + (lane >> 4) * 8;
  size_t dst = (size_t)idx * 8;
#pragma unroll
  for (int i = 0; i < 8; ++i) {
    float v = (n < NTAG) ? w2t[(size_t)n * 1024 + k0 + i] : 0.0f;
    unsigned short hi = f32_to_bf16_rn(v);
    unsigned short lo = f32_to_bf16_rn(v - bf16_to_f32(hi));
    o_hi[dst + i] = hi;
    o_lo[dst + i] = lo;
  }
}

// -------------------- persistent BiLSTM recurrence --------------------
// Grid = 256 WGs, 1/CU. WG = (dir, js(16 j's), bq(16 batch rows)).
// HF[dir][slot 514][bq4][kq16][lane64][8] hi/lo; slot = t+1; slots 0,513 zeroed.
// r5 protocol: flag[dir][bq][js] = steps completed (plain agent store, owned
// line). Wave w's h-GEMM only uses kq in [4w,4w+4) => j in [128w,128w+128) =>
// producers js in [8w,8w+8): each wave polls only ITS 8 producers, after the
// (independent) x-GEMM, so x-work overlaps producer skew. h slots are
// per-step distinct, so no two-sided rendezvous is needed.
__global__ __launch_bounds__(256, 1)
void lstm_rec(const unsigned short* __restrict__ xf_hi,
              const unsigned short* __restrict__ xf_lo,
              const unsigned short* __restrict__ wf_hi,
              const unsigned short* __restrict__ wf_lo,
              const float* __restrict__ bias_f,
              const float* __restrict__ bias_b,
              unsigned short* __restrict__ hf_hi,
              unsigned short* __restrict__ hf_lo,
              unsigned int* __restrict__ flags) {
  extern __shared__ unsigned char smem[];
  unsigned short* w_lds = (unsigned short*)smem;      // Whh_hi [0,64K) + Wih_hi [64K,128K)
  float* scratch = (float*)(smem + 131072);           // [wave4][nt4][lane64][4] = 16 KB

  int wg  = blockIdx.x;
  int dir = wg >> 7;
  int js  = (wg >> 2) & 31;
  int bq  = wg & 3;
  int tid  = threadIdx.x;
  int wave = tid >> 6;
  int lane = tid & 63;

  {
    const uint4* s0 = (const uint4*)wf_hi + ((size_t)(dir * 2 + 0) * 32 + js) * 4096;
    const uint4* s1 = (const uint4*)wf_hi + ((size_t)(dir * 2 + 1) * 32 + js) * 4096;
    uint4* d = (uint4*)w_lds;
    for (int i = tid; i < 4096; i += 256) { d[i] = s0[i]; d[4096 + i] = s1[i]; }
  }

  // preload step-invariant lo-weight fragments into registers/AGPRs (this
  // wave's kq slice: 4 kq x 4 nt x 2 matrices = 32 short8)
  short8 wlo_h[4][4], wlo_x[4][4];
#pragma unroll
  for (int q = 0; q < 4; ++q) {
    int kq = wave * 4 + q;
#pragma unroll
    for (int nt = 0; nt < 4; ++nt) {
      wlo_h[q][nt] = *(const short8*)(wf_lo +
            ((((((size_t)dir * 2 + 0) * 32 + js) * 4 + nt) * 16 + kq) * 64 + lane) * 8);
      wlo_x[q][nt] = *(const short8*)(wf_lo +
            ((((((size_t)dir * 2 + 1) * 32 + js) * 4 + nt) * 16 + kq) * 64 + lane) * 8);
    }
  }
  __syncthreads();

  int sm = tid >> 4;                 // local batch row 0..15
  int sj = tid & 15;                 // local j 0..15
  int jglob = js * 16 + sj;
  const float* bias = dir ? bias_b : bias_f;
  float bias_g[4];
#pragma unroll
  for (int g = 0; g < 4; ++g) bias_g[g] = bias[g * 512 + jglob];
  float c_state = 0.0f;

  // h write address pieces (constant per thread)
  int kqh   = jglob >> 5;
  int lane2 = ((jglob >> 3) & 3) * 16 + sm;
  int jrem  = jglob & 7;
  // wave w polls producers js in [8*wave, 8*wave+8), lanes 0..7
  const unsigned int* wavefp =
      flags + ((size_t)(dir * 4 + bq) * 32 + (8 * wave + (lane & 7))) * 16;
  unsigned int* myflag = flags + ((size_t)(dir * 4 + bq) * 32 + js) * 16;

  for (int s = 0; s < T_LEN; ++s) {
    int t = dir ? (T_LEN - 1 - s) : s;
    int rslot = dir ? (t + 2) : t;   // h[t+1] (bwd) / h[t-1] (fwd); zeros at s==0

    f32x4 acc[4];
#pragma unroll
    for (int nt = 0; nt < 4; ++nt) { f32x4 z = {0.f, 0.f, 0.f, 0.f}; acc[nt] = z; }

    // x-part GEMM (independent of peers): Wih_hi from LDS, Wih_lo from regs
    short8 xh[4], xl[4];
#pragma unroll
    for (int q = 0; q < 4; ++q) {
      int kq = wave * 4 + q;
      size_t xoff = ((((size_t)t * 4 + bq) * 16 + kq) * 64 + lane) * 8;
      xh[q] = *(const short8*)(xf_hi + xoff);
      xl[q] = *(const short8*)(xf_lo + xoff);
    }
#pragma unroll
    for (int q = 0; q < 4; ++q) {
      int kq = wave * 4 + q;
#pragma unroll
      for (int nt = 0; nt < 4; ++nt) {
        short8 bh = *(const short8*)&w_lds[((((size_t)(1 * 4 + nt)) * 16 + kq) * 64 + lane) * 8];
        acc[nt] = mfma16(xh[q], bh, acc[nt]);
        acc[nt] = mfma16(xh[q], wlo_x[q][nt], acc[nt]);
        acc[nt] = mfma16(xl[q], bh, acc[nt]);
      }
    }

    // poll MY 8 producers for step s-1 completion (flag >= s); overlaps skew
    if (s > 0) {
      unsigned tgt = (unsigned)s;
      int guard = 0;
      for (;;) {
        unsigned v = tgt;
        if (lane < 8) v = __hip_atomic_load(wavefp, __ATOMIC_RELAXED, __HIP_MEMORY_SCOPE_AGENT);
        if (__ballot(v < tgt) == 0ull) break;
        if (++guard > 4000000) break;
      }
    }

    // h-frag sc1 loads (LLC-fresh after flag observed)
    short8 hh[4], hl[4];
    {
      const short8* bh = (const short8*)hf_hi + ((((size_t)dir * 514 + rslot) * 4 + bq) * 16) * 64;
      const short8* bl = (const short8*)hf_lo + ((((size_t)dir * 514 + rslot) * 4 + bq) * 16) * 64;
#pragma unroll
      for (int q = 0; q < 4; ++q) {
        int kq = wave * 4 + q;
        ld_sc((const void*)(bh + kq * 64 + lane), hh[q]);
        ld_sc((const void*)(bl + kq * 64 + lane), hl[q]);
      }
    }
    wait_all(hh[0], hh[1], hh[2], hh[3], hl[0], hl[1], hl[2], hl[3]);

    // h-part GEMM: Whh_hi from LDS, Whh_lo from regs
#pragma unroll
    for (int q = 0; q < 4; ++q) {
      int kq = wave * 4 + q;
#pragma unroll
      for (int nt = 0; nt < 4; ++nt) {
        short8 bh = *(const short8*)&w_lds[((((size_t)(0 * 4 + nt)) * 16 + kq) * 64 + lane) * 8];
        acc[nt] = mfma16(hh[q], bh, acc[nt]);
        acc[nt] = mfma16(hh[q], wlo_h[q][nt], acc[nt]);
        acc[nt] = mfma16(hl[q], bh, acc[nt]);
      }
    }

    // cross-wave K-reduction via LDS
#pragma unroll
    for (int nt = 0; nt < 4; ++nt)
      *(f32x4*)&scratch[((size_t)(wave * 4 + nt) * 64 + lane) * 4] = acc[nt];
    __syncthreads();

    int lidx = (((sm >> 2) * 16) + sj) * 4 + (sm & 3);
    float g4[4];
#pragma unroll
    for (int g = 0; g < 4; ++g) {
      float v = bias_g[g];
#pragma unroll
      for (int w = 0; w < 4; ++w) v += scratch[(w * 4 + g) * 256 + lidx];
      g4[g] = v;
    }
    float i_s = 1.0f / (1.0f + expf(-g4[0]));
    float f_s = 1.0f / (1.0f + expf(-g4[1]));
    float g_t = tanhf(g4[2]);
    float o_s = 1.0f / (1.0f + expf(-g4[3]));
    c_state = f_s * c_state + i_s * g_t;
    float h = o_s * tanhf(c_state);

    // pack neighbor pairs (sj even/odd share a 4B word), agent-scope u32 store
    unsigned int vhi = f32_to_bf16_rn(h);
    unsigned int vlo = f32_to_bf16_rn(h - bf16_to_f32((unsigned short)vhi));
    unsigned int phi = (unsigned int)__shfl_xor((int)vhi, 1);
    unsigned int plo = (unsigned int)__shfl_xor((int)vlo, 1);
    if ((sj & 1) == 0) {
      unsigned int whi = vhi | (phi << 16);
      unsigned int wlo = vlo | (plo << 16);
      size_t foff = ((((size_t)dir * 514 + (t + 1)) * 4 + bq) * 16 + kqh);
      size_t eoff = (foff * 64 + lane2) * 8 + jrem;     // even u16 index
      __hip_atomic_store((unsigned int*)(hf_hi + eoff), whi,
                         __ATOMIC_RELAXED, __HIP_MEMORY_SCOPE_AGENT);
      __hip_atomic_store((unsigned int*)(hf_lo + eoff), wlo,
                         __ATOMIC_RELAXED, __HIP_MEMORY_SCOPE_AGENT);
    }

    asm volatile("s_waitcnt vmcnt(0)" ::: "memory");   // h stores acked at LLC
    __syncthreads();                                   // all 4 waves' stores acked
    if (tid == 0)                                      // owned flag: plain store
      __hip_atomic_store(myflag, (unsigned)(s + 1),
                         __ATOMIC_RELAXED, __HIP_MEMORY_SCOPE_AGENT);
  }
}

// -------------------- emissions: feats = [h_f|h_b] @ W_h2t.T + b --------------------
__global__ __launch_bounds__(256) void feats_kernel(const unsigned short* __restrict__ hf_hi,
                                                    const unsigned short* __restrict__ hf_lo,
                                                    const unsigned short* __restrict__ w2t_hi,
                                                    const unsigned short* __restrict__ w2t_lo,
                                                    const float* __restrict__ b_h2t,
                                                    float* __restrict__ feats) {
  int t = blockIdx.x;
  int wave = threadIdx.x >> 6;       // = mt (batch tile)
  int lane = threadIdx.x & 63;
  f32x4 acc[2];
#pragma unroll
  for (int nt = 0; nt < 2; ++nt) { f32x4 z = {0.f, 0.f, 0.f, 0.f}; acc[nt] = z; }

  for (int kq = 0; kq < 32; ++kq) {
    int dir = kq >> 4, kqi = kq & 15;
    size_t af = (((((size_t)dir * 514 + (t + 1)) * 4 + wave) * 16 + kqi) * 64 + lane) * 8;
    short8 ah = *(const short8*)(hf_hi + af);
    short8 al = *(const short8*)(hf_lo + af);
#pragma unroll
    for (int nt = 0; nt < 2; ++nt) {
      size_t bf = (((size_t)nt * 32 + kq) * 64 + lane) * 8;
      short8 bh = *(const short8*)(w2t_hi + bf);
      short8 bl = *(const short8*)(w2t_lo + bf);
      acc[nt] = mfma16(ah, bh, acc[nt]);
      acc[nt] = mfma16(ah, bl, acc[nt]);
      acc[nt] = mfma16(al, bh, acc[nt]);
    }
  }
  int quad = lane >> 4, col = lane & 15;
#pragma unroll
  for (int nt = 0; nt < 2; ++nt) {
    int n = nt * 16 + col;
    if (n < NTAG) {
      float bb = b_h2t[n];
#pragma unroll
      for (int r = 0; r < 4; ++r) {
        int b = wave * 16 + quad * 4 + r;
        feats[((size_t)b * T_LEN + t) * 24 + n] = acc[nt][r] + bb;
      }
    }
  }
}

// -------------------- Viterbi (exact semantics; fv + trans row in registers) ----------
__global__ __launch_bounds__(64) void viterbi_kernel(const float* __restrict__ feats,
                                                     const int* __restrict__ seq_len,
                                                     const float* __restrict__ trans,
                                                     float* __restrict__ out) {
  int b = blockIdx.x;
  int lane = threadIdx.x;            // one wave per batch row
  __shared__ unsigned char bp_s[T_LEN * 24];
  bool tag_lane = lane < NTAG;
  float tr_reg[NTAG];                // tr_reg[k] = trans[next=lane][prev=k]
#pragma unroll 1
  for (int k = 0; k < NTAG; ++k) tr_reg[k] = tag_lane ? trans[lane * NTAG + k] : NEGV;
  float fv = (lane == 1) ? 0.0f : NEGV;    // START = 1; lanes >= NTAG stay NEGV
  int L = seq_len[b];
  float ft = tag_lane ? feats[((size_t)b * T_LEN) * 24 + lane] : 0.0f;
#pragma unroll 1
  for (int t = 0; t < T_LEN; ++t) {
    float ftn = 0.0f;
    if (t + 1 < T_LEN && tag_lane) ftn = feats[((size_t)b * T_LEN + t + 1) * 24 + lane];
    float best = __shfl(fv, 0) + tr_reg[0];
    int arg = 0;
#pragma unroll 1
    for (int k = 1; k < NTAG; ++k) {
      float v = __shfl(fv, k) + tr_reg[k];
      if (v > best) { best = v; arg = k; }    // strict > keeps FIRST max (jnp.argmax)
    }
    bool active = (t < L);
    if (tag_lane) bp_s[t * 24 + lane] = (unsigned char)(active ? arg : lane);
    fv = active ? (best + ft) : fv;
    ft = ftn;
  }
  // terminal: term[k] = fv[k] + trans[END][k]; argmax (first occurrence)
  float term = tag_lane ? (fv + trans[2 * NTAG + lane]) : NEGV;
  float bv = term; int bi = lane;
#pragma unroll
  for (int off = 32; off; off >>= 1) {
    float ov = __shfl_down(bv, off);
    int oi = __shfl_down(bi, off);
    if (ov > bv || (ov == bv && oi < bi)) { bv = ov; bi = oi; }
  }
  __syncthreads();                    // bp_s writes visible for the backtrack
  if (lane == 0) {
    out[b] = bv;
    int tag = bi;
    out[64 + (size_t)b * T_LEN + (T_LEN - 1)] = (float)tag;
    for (int t = T_LEN - 2; t >= 0; --t) {
      tag = bp_s[(t + 1) * 24 + tag];
      out[64 + (size_t)b * T_LEN + t] = (float)tag;
    }
  }
}

// -------------------- launch --------------------
extern "C" void kernel_launch(void* const* d_in, const int* in_sizes, int n_in,
                              void* d_out, int out_size, void* d_ws, size_t ws_size,
                              hipStream_t stream) {
  const float* texts   = (const float*)d_in[0];
  const int*   seq_len = (const int*)d_in[1];
  const float* Wih_f   = (const float*)d_in[2];
  const float* Whh_f   = (const float*)d_in[3];
  const float* b_f     = (const float*)d_in[4];
  const float* Wih_b   = (const float*)d_in[5];
  const float* Whh_b   = (const float*)d_in[6];
  const float* b_b     = (const float*)d_in[7];
  const float* W_h2t   = (const float*)d_in[8];
  const float* b_h2t   = (const float*)d_in[9];
  const float* trans   = (const float*)d_in[10];
  (void)in_sizes; (void)n_in; (void)out_size; (void)ws_size;

  unsigned char* ws = (unsigned char*)d_ws;
  size_t off = 0;
  auto alloc = [&](size_t bytes) -> void* {
    void* p = ws + off;
    off += (bytes + 255) & ~(size_t)255;
    return p;
  };
  // total ~218.4 MB — within the proven budget
  unsigned short* xf_hi  = (unsigned short*)alloc(33554432);
  unsigned short* xf_lo  = (unsigned short*)alloc(33554432);
  unsigned short* wf_hi  = (unsigned short*)alloc(8388608);
  unsigned short* wf_lo  = (unsigned short*)alloc(8388608);
  unsigned short* hf_hi  = (unsigned short*)alloc(67371008);   // 2*514*4096 frags *16B
  unsigned short* hf_lo  = (unsigned short*)alloc(67371008);
  unsigned short* w2t_hi = (unsigned short*)alloc(65536);
  unsigned short* w2t_lo = (unsigned short*)alloc(65536);
  float*          feats  = (float*)alloc(3145728);             // [64][512][24] f32
  unsigned int*   flags  = (unsigned int*)alloc(16384);        // [2][4][32] @64B stride

  // zero flags and the h boundary slots (slot 0 and 513 per dir)
  hipMemsetAsync(flags, 0, 16384, stream);
  for (int d = 0; d < 2; ++d) {
    hipMemsetAsync(hf_hi + ((size_t)d * 514 + 0)   * 32768, 0, 65536, stream);
    hipMemsetAsync(hf_hi + ((size_t)d * 514 + 513) * 32768, 0, 65536, stream);
    hipMemsetAsync(hf_lo + ((size_t)d * 514 + 0)   * 32768, 0, 65536, stream);
    hipMemsetAsync(hf_lo + ((size_t)d * 514 + 513) * 32768, 0, 65536, stream);
  }

  hipFuncSetAttribute((const void*)lstm_rec,
                      hipFuncAttributeMaxDynamicSharedMemorySize, 147456);

  prep_xf<<<8192, 256, 0, stream>>>(texts, xf_hi, xf_lo);
  prep_wf<<<2048, 256, 0, stream>>>(Whh_f, Wih_f, Whh_b, Wih_b, wf_hi, wf_lo);
  prep_w2t<<<16, 256, 0, stream>>>(W_h2t, w2t_hi, w2t_lo);
  lstm_rec<<<256, 256, 147456, stream>>>(xf_hi, xf_lo, wf_hi, wf_lo,
                                         b_f, b_b, hf_hi, hf_lo, flags);
  feats_kernel<<<512, 256, 0, stream>>>(hf_hi, hf_lo, w2t_hi, w2t_lo, b_h2t, feats);
  viterbi_kernel<<<64, 64, 0, stream>>>(feats, seq_len, trans, (float*)d_out);
}

// Round 6
// 2647.552 us; speedup vs baseline: 3.6551x; 1.0985x over previous
//
#include <hip/hip_runtime.h>
#include <stdint.h>
#include <math.h>

#define T_LEN 512
#define BATCH 64
#define EMB   512
#define HID   512
#define NTAG  23
#define NEGV  -10000.0f

typedef __attribute__((ext_vector_type(4))) float f32x4;
typedef __attribute__((ext_vector_type(8))) short short8;

#define DEVI __device__ __forceinline__

DEVI unsigned short f32_to_bf16_rn(float f) {
  union { float f; uint32_t u; } v; v.f = f;
  uint32_t u = v.u;
  uint32_t r = u + 0x7FFFu + ((u >> 16) & 1u);
  return (unsigned short)(r >> 16);
}
DEVI float bf16_to_f32(unsigned short h) {
  union { float f; uint32_t u; } v; v.u = ((uint32_t)h) << 16;
  return v.f;
}

DEVI f32x4 mfma16(short8 a, short8 b, f32x4 c) {
  return __builtin_amdgcn_mfma_f32_16x16x32_bf16(a, b, c, 0, 0, 0);
}

// device-scope (LLC-coherent, cross-XCD) 16B load: sc1 bypasses the XCD L2.
DEVI void ld_sc(const void* p, short8& d) {
  asm volatile("global_load_dwordx4 %0, %1, off sc1" : "=v"(d) : "v"(p) : "memory");
}
DEVI void wait_all(short8& a0, short8& a1, short8& a2, short8& a3,
                   short8& b0, short8& b1, short8& b2, short8& b3) {
  asm volatile("s_waitcnt vmcnt(0)"
               : "+v"(a0), "+v"(a1), "+v"(a2), "+v"(a3),
                 "+v"(b0), "+v"(b1), "+v"(b2), "+v"(b3)
               :: "memory");
}

// fast activations: v_exp_f32 computes 2^x; v_rcp_f32 for the divide.
DEVI float fast_sigmoid(float x) {
  float e = exp2f(x * -1.44269504f);
  return __builtin_amdgcn_rcpf(1.0f + e);
}
DEVI float fast_tanh(float x) {
  float xc = fminf(fmaxf(x, -20.0f), 20.0f);   // avoid inf*(0) = NaN
  float t = exp2f(xc * -2.88539008f);
  return (1.0f - t) * __builtin_amdgcn_rcpf(1.0f + t);
}

// -------------------- fragment-layout packing kernels --------------------
// XF[t][mt4][kq16][lane64][8]  (A-frags of texts, hi/lo split)
__global__ __launch_bounds__(256) void prep_xf(const float* __restrict__ x,
                                               unsigned short* __restrict__ xf_hi,
                                               unsigned short* __restrict__ xf_lo) {
  int idx = blockIdx.x * 256 + threadIdx.x;       // 512*4*16*64 = 2097152
  int lane = idx & 63;
  int kq   = (idx >> 6) & 15;
  int mt   = (idx >> 10) & 3;
  int t    = idx >> 12;
  int b  = mt * 16 + (lane & 15);
  int e0 = kq * 32 + (lane >> 4) * 8;
  const float* src = x + ((size_t)b * T_LEN + t) * EMB + e0;
  size_t dst = (size_t)idx * 8;
#pragma unroll
  for (int i = 0; i < 8; ++i) {
    float v = src[i];
    unsigned short hi = f32_to_bf16_rn(v);
    unsigned short lo = f32_to_bf16_rn(v - bf16_to_f32(hi));
    xf_hi[dst + i] = hi;
    xf_lo[dst + i] = lo;
  }
}

// WF[dir2][mat2][js32][nt4][kq16][lane64][8]; mat0 = Whh, mat1 = Wih
__global__ __launch_bounds__(256) void prep_wf(const float* __restrict__ whh_f,
                                               const float* __restrict__ wih_f,
                                               const float* __restrict__ whh_b,
                                               const float* __restrict__ wih_b,
                                               unsigned short* __restrict__ wf_hi,
                                               unsigned short* __restrict__ wf_lo) {
  int idx = blockIdx.x * 256 + threadIdx.x;       // 2*2*32*4*16*64 = 524288
  int lane = idx & 63;
  int kq   = (idx >> 6) & 15;
  int nt   = (idx >> 10) & 3;
  int js   = (idx >> 12) & 31;
  int mat  = (idx >> 17) & 1;
  int dir  = (idx >> 18) & 1;
  const float* W = dir ? (mat ? wih_b : whh_b) : (mat ? wih_f : whh_f);
  int row = nt * 512 + js * 16 + (lane & 15);     // gate-major rows of [2048][512]
  int k0  = kq * 32 + (lane >> 4) * 8;
  const float* src = W + (size_t)row * 512 + k0;
  size_t dst = (size_t)idx * 8;
#pragma unroll
  for (int i = 0; i < 8; ++i) {
    float v = src[i];
    unsigned short hi = f32_to_bf16_rn(v);
    unsigned short lo = f32_to_bf16_rn(v - bf16_to_f32(hi));
    wf_hi[dst + i] = hi;
    wf_lo[dst + i] = lo;
  }
}

// W2T[nt2][kq32][lane64][8]  (B-frags of W_h2t [23][1024], N padded to 32)
__global__ __launch_bounds__(256) void prep_w2t(const float* __restrict__ w2t,
                                                unsigned short* __restrict__ o_hi,
                                                unsigned short* __restrict__ o_lo) {
  int idx = blockIdx.x * 256 + threadIdx.x;       // 2*32*64 = 4096
  int lane = idx & 63;
  int kq   = (idx >> 6) & 31;
  int nt   = (idx >> 11) & 1;
  int n  = nt * 16 + (lane & 15);
  int k0 = kq * 32 + (lane >> 4) * 8;
  size_t dst = (size_t)idx * 8;
#pragma unroll
  for (int i = 0; i < 8; ++i) {
    float v = (n < NTAG) ? w2t[(size_t)n * 1024 + k0 + i] : 0.0f;
    unsigned short hi = f32_to_bf16_rn(v);
    unsigned short lo = f32_to_bf16_rn(v - bf16_to_f32(hi));
    o_hi[dst + i] = hi;
    o_lo[dst + i] = lo;
  }
}

// -------------------- sentinel fill: bf16 +inf (0x7F80) into h slots 1..512 --------
// h = sigmoid*tanh is always in (-1,1): neither hi nor lo can ever be inf, so
// "fragment word != inf-pattern" certifies the producer's 4B store has landed.
__global__ __launch_bounds__(256) void fill_sent(uint4* __restrict__ hi,
                                                 uint4* __restrict__ lo) {
  const uint4 v = {0x7F807F80u, 0x7F807F80u, 0x7F807F80u, 0x7F807F80u};
  unsigned idx = blockIdx.x * 256 + threadIdx.x;     // 1048576 threads
#pragma unroll
  for (int i = 0; i < 4; ++i) {
    unsigned k = idx + (unsigned)i * 1048576u;       // uint4 index < 4194304
    unsigned word = k << 2;                          // u32 index within 2*512 slots
    unsigned dir  = word >> 23;                      // / (512*16384)
    unsigned rem  = word & 8388607u;
    unsigned slot = 1u + (rem >> 14);                // 1..512
    unsigned off  = rem & 16383u;
    size_t dst = (((size_t)(dir * 514 + slot) << 14) + off) >> 2;  // uint4 idx
    hi[dst] = v;
    lo[dst] = v;
  }
}

// -------------------- persistent BiLSTM recurrence --------------------
// Grid = 256 WGs, 1/CU. WG = (dir, js(16 j's), bq(16 batch rows)).
// HF[dir][slot 514][bq4][kq16][lane64][8] hi/lo; slot = t+1; slots 0,513 zeroed,
// slots 1..512 sentinel-filled. r6 protocol: NO flags, NO producer-side wait —
// consumers poll the h data itself until no word matches the inf sentinel.
// Detect and load are one LLC round trip; producers free-run.
__global__ __launch_bounds__(256, 1)
void lstm_rec(const unsigned short* __restrict__ xf_hi,
              const unsigned short* __restrict__ xf_lo,
              const unsigned short* __restrict__ wf_hi,
              const unsigned short* __restrict__ wf_lo,
              const float* __restrict__ bias_f,
              const float* __restrict__ bias_b,
              unsigned short* __restrict__ hf_hi,
              unsigned short* __restrict__ hf_lo) {
  extern __shared__ unsigned char smem[];
  unsigned short* w_lds = (unsigned short*)smem;      // Whh_hi [0,64K) + Wih_hi [64K,128K)
  float* scratch = (float*)(smem + 131072);           // [wave4][nt4][lane64][4] = 16 KB

  int wg  = blockIdx.x;
  int dir = wg >> 7;
  int js  = (wg >> 2) & 31;
  int bq  = wg & 3;
  int tid  = threadIdx.x;
  int wave = tid >> 6;
  int lane = tid & 63;

  {
    const uint4* s0 = (const uint4*)wf_hi + ((size_t)(dir * 2 + 0) * 32 + js) * 4096;
    const uint4* s1 = (const uint4*)wf_hi + ((size_t)(dir * 2 + 1) * 32 + js) * 4096;
    uint4* d = (uint4*)w_lds;
    for (int i = tid; i < 4096; i += 256) { d[i] = s0[i]; d[4096 + i] = s1[i]; }
  }

  // preload step-invariant lo-weight fragments into regs/AGPRs
  short8 wlo_h[4][4], wlo_x[4][4];
#pragma unroll
  for (int q = 0; q < 4; ++q) {
    int kq = wave * 4 + q;
#pragma unroll
    for (int nt = 0; nt < 4; ++nt) {
      wlo_h[q][nt] = *(const short8*)(wf_lo +
            ((((((size_t)dir * 2 + 0) * 32 + js) * 4 + nt) * 16 + kq) * 64 + lane) * 8);
      wlo_x[q][nt] = *(const short8*)(wf_lo +
            ((((((size_t)dir * 2 + 1) * 32 + js) * 4 + nt) * 16 + kq) * 64 + lane) * 8);
    }
  }
  __syncthreads();

  int sm = tid >> 4;                 // local batch row 0..15
  int sj = tid & 15;                 // local j 0..15
  int jglob = js * 16 + sj;
  const float* bias = dir ? bias_b : bias_f;
  float bias_g[4];
#pragma unroll
  for (int g = 0; g < 4; ++g) bias_g[g] = bias[g * 512 + jglob];
  float c_state = 0.0f;

  // h write address pieces (constant per thread)
  int kqh   = jglob >> 5;
  int lane2 = ((jglob >> 3) & 3) * 16 + sm;
  int jrem  = jglob & 7;

  for (int s = 0; s < T_LEN; ++s) {
    int t = dir ? (T_LEN - 1 - s) : s;
    int rslot = dir ? (t + 2) : t;   // h[t+1] (bwd) / h[t-1] (fwd); zeros at s==0

    f32x4 acc[4];
#pragma unroll
    for (int nt = 0; nt < 4; ++nt) { f32x4 z = {0.f, 0.f, 0.f, 0.f}; acc[nt] = z; }

    // x-part GEMM first (independent of peers): Wih_hi LDS, Wih_lo regs
    short8 xh[4], xl[4];
#pragma unroll
    for (int q = 0; q < 4; ++q) {
      int kq = wave * 4 + q;
      size_t xoff = ((((size_t)t * 4 + bq) * 16 + kq) * 64 + lane) * 8;
      xh[q] = *(const short8*)(xf_hi + xoff);
      xl[q] = *(const short8*)(xf_lo + xoff);
    }
#pragma unroll
    for (int q = 0; q < 4; ++q) {
      int kq = wave * 4 + q;
#pragma unroll
      for (int nt = 0; nt < 4; ++nt) {
        short8 bh = *(const short8*)&w_lds[((((size_t)(1 * 4 + nt)) * 16 + kq) * 64 + lane) * 8];
        acc[nt] = mfma16(xh[q], bh, acc[nt]);
        acc[nt] = mfma16(xh[q], wlo_x[q][nt], acc[nt]);
        acc[nt] = mfma16(xl[q], bh, acc[nt]);
      }
    }

    // poll-load h fragments: retry until no u16 equals the inf sentinel.
    short8 hh[4], hl[4];
    {
      const short8* bhp = (const short8*)hf_hi + ((((size_t)dir * 514 + rslot) * 4 + bq) * 16) * 64;
      const short8* blp = (const short8*)hf_lo + ((((size_t)dir * 514 + rslot) * 4 + bq) * 16) * 64;
      int guard = 0;
      for (;;) {
#pragma unroll
        for (int q = 0; q < 4; ++q) {
          int kq = wave * 4 + q;
          ld_sc((const void*)(bhp + kq * 64 + lane), hh[q]);
          ld_sc((const void*)(blp + kq * 64 + lane), hl[q]);
        }
        wait_all(hh[0], hh[1], hh[2], hh[3], hl[0], hl[1], hl[2], hl[3]);
        uint32_t bad = 0;
#pragma unroll
        for (int q = 0; q < 4; ++q) {
          const uint32_t* wh = (const uint32_t*)&hh[q];
          const uint32_t* wl = (const uint32_t*)&hl[q];
#pragma unroll
          for (int i = 0; i < 4; ++i) {
            uint32_t x = wh[i] ^ 0x7F807F80u;
            bad |= (x - 0x00010001u) & ~x & 0x80008000u;   // zero-half <=> sentinel
            uint32_t y = wl[i] ^ 0x7F807F80u;
            bad |= (y - 0x00010001u) & ~y & 0x80008000u;
          }
        }
        if (__ballot(bad != 0) == 0ull) break;
        if (++guard > 2000000) break;
        __builtin_amdgcn_s_sleep(1);
      }
    }

    // h-part GEMM: Whh_hi LDS, Whh_lo regs
#pragma unroll
    for (int q = 0; q < 4; ++q) {
      int kq = wave * 4 + q;
#pragma unroll
      for (int nt = 0; nt < 4; ++nt) {
        short8 bh = *(const short8*)&w_lds[((((size_t)(0 * 4 + nt)) * 16 + kq) * 64 + lane) * 8];
        acc[nt] = mfma16(hh[q], bh, acc[nt]);
        acc[nt] = mfma16(hh[q], wlo_h[q][nt], acc[nt]);
        acc[nt] = mfma16(hl[q], bh, acc[nt]);
      }
    }

    // cross-wave K-reduction via LDS
#pragma unroll
    for (int nt = 0; nt < 4; ++nt)
      *(f32x4*)&scratch[((size_t)(wave * 4 + nt) * 64 + lane) * 4] = acc[nt];
    __syncthreads();

    int lidx = (((sm >> 2) * 16) + sj) * 4 + (sm & 3);
    float g4[4];
#pragma unroll
    for (int g = 0; g < 4; ++g) {
      float v = bias_g[g];
#pragma unroll
      for (int w = 0; w < 4; ++w) v += scratch[(w * 4 + g) * 256 + lidx];
      g4[g] = v;
    }
    __syncthreads();                 // scratch reads done before next step's writes

    float i_s = fast_sigmoid(g4[0]);
    float f_s = fast_sigmoid(g4[1]);
    float g_t = fast_tanh(g4[2]);
    float o_s = fast_sigmoid(g4[3]);
    c_state = f_s * c_state + i_s * g_t;
    float h = o_s * fast_tanh(c_state);

    // pack neighbor pairs (sj even/odd share a 4B word), agent-scope u32 store;
    // NO wait, NO barrier, NO flag — the data itself is the signal.
    unsigned int vhi = f32_to_bf16_rn(h);
    unsigned int vlo = f32_to_bf16_rn(h - bf16_to_f32((unsigned short)vhi));
    unsigned int phi = (unsigned int)__shfl_xor((int)vhi, 1);
    unsigned int plo = (unsigned int)__shfl_xor((int)vlo, 1);
    if ((sj & 1) == 0) {
      unsigned int whi = vhi | (phi << 16);
      unsigned int wlo = vlo | (plo << 16);
      size_t foff = ((((size_t)dir * 514 + (t + 1)) * 4 + bq) * 16 + kqh);
      size_t eoff = (foff * 64 + lane2) * 8 + jrem;     // even u16 index
      __hip_atomic_store((unsigned int*)(hf_hi + eoff), whi,
                         __ATOMIC_RELAXED, __HIP_MEMORY_SCOPE_AGENT);
      __hip_atomic_store((unsigned int*)(hf_lo + eoff), wlo,
                         __ATOMIC_RELAXED, __HIP_MEMORY_SCOPE_AGENT);
    }
  }
}

// -------------------- emissions: feats = [h_f|h_b] @ W_h2t.T + b --------------------
__global__ __launch_bounds__(256) void feats_kernel(const unsigned short* __restrict__ hf_hi,
                                                    const unsigned short* __restrict__ hf_lo,
                                                    const unsigned short* __restrict__ w2t_hi,
                                                    const unsigned short* __restrict__ w2t_lo,
                                                    const float* __restrict__ b_h2t,
                                                    float* __restrict__ feats) {
  int t = blockIdx.x;
  int wave = threadIdx.x >> 6;       // = mt (batch tile)
  int lane = threadIdx.x & 63;
  f32x4 acc[2];
#pragma unroll
  for (int nt = 0; nt < 2; ++nt) { f32x4 z = {0.f, 0.f, 0.f, 0.f}; acc[nt] = z; }

  for (int kq = 0; kq < 32; ++kq) {
    int dir = kq >> 4, kqi = kq & 15;
    size_t af = (((((size_t)dir * 514 + (t + 1)) * 4 + wave) * 16 + kqi) * 64 + lane) * 8;
    short8 ah = *(const short8*)(hf_hi + af);
    short8 al = *(const short8*)(hf_lo + af);
#pragma unroll
    for (int nt = 0; nt < 2; ++nt) {
      size_t bf = (((size_t)nt * 32 + kq) * 64 + lane) * 8;
      short8 bh = *(const short8*)(w2t_hi + bf);
      short8 bl = *(const short8*)(w2t_lo + bf);
      acc[nt] = mfma16(ah, bh, acc[nt]);
      acc[nt] = mfma16(ah, bl, acc[nt]);
      acc[nt] = mfma16(al, bh, acc[nt]);
    }
  }
  int quad = lane >> 4, col = lane & 15;
#pragma unroll
  for (int nt = 0; nt < 2; ++nt) {
    int n = nt * 16 + col;
    if (n < NTAG) {
      float bb = b_h2t[n];
#pragma unroll
      for (int r = 0; r < 4; ++r) {
        int b = wave * 16 + quad * 4 + r;
        feats[((size_t)b * T_LEN + t) * 24 + n] = acc[nt][r] + bb;
      }
    }
  }
}

// -------------------- Viterbi (exact semantics; fv + trans row in registers) ----------
__global__ __launch_bounds__(64) void viterbi_kernel(const float* __restrict__ feats,
                                                     const int* __restrict__ seq_len,
                                                     const float* __restrict__ trans,
                                                     float* __restrict__ out) {
  int b = blockIdx.x;
  int lane = threadIdx.x;            // one wave per batch row
  __shared__ unsigned char bp_s[T_LEN * 24];
  bool tag_lane = lane < NTAG;
  float tr_reg[NTAG];                // tr_reg[k] = trans[next=lane][prev=k]
#pragma unroll 1
  for (int k = 0; k < NTAG; ++k) tr_reg[k] = tag_lane ? trans[lane * NTAG + k] : NEGV;
  float fv = (lane == 1) ? 0.0f : NEGV;    // START = 1; lanes >= NTAG stay NEGV
  int L = seq_len[b];
  float ft = tag_lane ? feats[((size_t)b * T_LEN) * 24 + lane] : 0.0f;
#pragma unroll 1
  for (int t = 0; t < T_LEN; ++t) {
    float ftn = 0.0f;
    if (t + 1 < T_LEN && tag_lane) ftn = feats[((size_t)b * T_LEN + t + 1) * 24 + lane];
    float best = __shfl(fv, 0) + tr_reg[0];
    int arg = 0;
#pragma unroll 1
    for (int k = 1; k < NTAG; ++k) {
      float v = __shfl(fv, k) + tr_reg[k];
      if (v > best) { best = v; arg = k; }    // strict > keeps FIRST max (jnp.argmax)
    }
    bool active = (t < L);
    if (tag_lane) bp_s[t * 24 + lane] = (unsigned char)(active ? arg : lane);
    fv = active ? (best + ft) : fv;
    ft = ftn;
  }
  // terminal: term[k] = fv[k] + trans[END][k]; argmax (first occurrence)
  float term = tag_lane ? (fv + trans[2 * NTAG + lane]) : NEGV;
  float bv = term; int bi = lane;
#pragma unroll
  for (int off = 32; off; off >>= 1) {
    float ov = __shfl_down(bv, off);
    int oi = __shfl_down(bi, off);
    if (ov > bv || (ov == bv && oi < bi)) { bv = ov; bi = oi; }
  }
  __syncthreads();                    // bp_s writes visible for the backtrack
  if (lane == 0) {
    out[b] = bv;
    int tag = bi;
    out[64 + (size_t)b * T_LEN + (T_LEN - 1)] = (float)tag;
    for (int t = T_LEN - 2; t >= 0; --t) {
      tag = bp_s[(t + 1) * 24 + tag];
      out[64 + (size_t)b * T_LEN + t] = (float)tag;
    }
  }
}

// -------------------- launch --------------------
extern "C" void kernel_launch(void* const* d_in, const int* in_sizes, int n_in,
                              void* d_out, int out_size, void* d_ws, size_t ws_size,
                              hipStream_t stream) {
  const float* texts   = (const float*)d_in[0];
  const int*   seq_len = (const int*)d_in[1];
  const float* Wih_f   = (const float*)d_in[2];
  const float* Whh_f   = (const float*)d_in[3];
  const float* b_f     = (const float*)d_in[4];
  const float* Wih_b   = (const float*)d_in[5];
  const float* Whh_b   = (const float*)d_in[6];
  const float* b_b     = (const float*)d_in[7];
  const float* W_h2t   = (const float*)d_in[8];
  const float* b_h2t   = (const float*)d_in[9];
  const float* trans   = (const float*)d_in[10];
  (void)in_sizes; (void)n_in; (void)out_size; (void)ws_size;

  unsigned char* ws = (unsigned char*)d_ws;
  size_t off = 0;
  auto alloc = [&](size_t bytes) -> void* {
    void* p = ws + off;
    off += (bytes + 255) & ~(size_t)255;
    return p;
  };
  // total ~218.4 MB — within the proven budget
  unsigned short* xf_hi  = (unsigned short*)alloc(33554432);
  unsigned short* xf_lo  = (unsigned short*)alloc(33554432);
  unsigned short* wf_hi  = (unsigned short*)alloc(8388608);
  unsigned short* wf_lo  = (unsigned short*)alloc(8388608);
  unsigned short* hf_hi  = (unsigned short*)alloc(67371008);   // 2*514*4096 frags *16B
  unsigned short* hf_lo  = (unsigned short*)alloc(67371008);
  unsigned short* w2t_hi = (unsigned short*)alloc(65536);
  unsigned short* w2t_lo = (unsigned short*)alloc(65536);
  float*          feats  = (float*)alloc(3145728);             // [64][512][24] f32

  // zero the h boundary slots (slot 0 and 513 per dir)
  for (int d = 0; d < 2; ++d) {
    hipMemsetAsync(hf_hi + ((size_t)d * 514 + 0)   * 32768, 0, 65536, stream);
    hipMemsetAsync(hf_hi + ((size_t)d * 514 + 513) * 32768, 0, 65536, stream);
    hipMemsetAsync(hf_lo + ((size_t)d * 514 + 0)   * 32768, 0, 65536, stream);
    hipMemsetAsync(hf_lo + ((size_t)d * 514 + 513) * 32768, 0, 65536, stream);
  }

  hipFuncSetAttribute((const void*)lstm_rec,
                      hipFuncAttributeMaxDynamicSharedMemorySize, 147456);

  fill_sent<<<4096, 256, 0, stream>>>((uint4*)hf_hi, (uint4*)hf_lo);
  prep_xf<<<8192, 256, 0, stream>>>(texts, xf_hi, xf_lo);
  prep_wf<<<2048, 256, 0, stream>>>(Whh_f, Wih_f, Whh_b, Wih_b, wf_hi, wf_lo);
  prep_w2t<<<16, 256, 0, stream>>>(W_h2t, w2t_hi, w2t_lo);
  lstm_rec<<<256, 256, 147456, stream>>>(xf_hi, xf_lo, wf_hi, wf_lo,
                                         b_f, b_b, hf_hi, hf_lo);
  feats_kernel<<<512, 256, 0, stream>>>(hf_hi, hf_lo, w2t_hi, w2t_lo, b_h2t, feats);
  viterbi_kernel<<<64, 64, 0, stream>>>(feats, seq_len, trans, (float*)d_out);
}

// Round 7
// 2137.728 us; speedup vs baseline: 4.5268x; 1.2385x over previous
//
#include <hip/hip_runtime.h>
#include <stdint.h>
#include <math.h>

#define T_LEN 512
#define BATCH 64
#define EMB   512
#define HID   512
#define NTAG  23
#define NEGV  -10000.0f

typedef __attribute__((ext_vector_type(4))) float f32x4;
typedef __attribute__((ext_vector_type(8))) short short8;

#define DEVI __device__ __forceinline__

DEVI unsigned short f32_to_bf16_rn(float f) {
  union { float f; uint32_t u; } v; v.f = f;
  uint32_t u = v.u;
  uint32_t r = u + 0x7FFFu + ((u >> 16) & 1u);
  return (unsigned short)(r >> 16);
}
DEVI float bf16_to_f32(unsigned short h) {
  union { float f; uint32_t u; } v; v.u = ((uint32_t)h) << 16;
  return v.f;
}

DEVI f32x4 mfma16(short8 a, short8 b, f32x4 c) {
  return __builtin_amdgcn_mfma_f32_16x16x32_bf16(a, b, c, 0, 0, 0);
}

// device-scope (LLC-coherent, cross-XCD) 16B load: sc1 bypasses the XCD L2.
DEVI void ld_sc(const void* p, short8& d) {
  asm volatile("global_load_dwordx4 %0, %1, off sc1" : "=v"(d) : "v"(p) : "memory");
}
// normal cached 16B load (L1/L2 path) — asm so WE control vmcnt accounting
DEVI void ld_l2(const void* p, short8& d) {
  asm volatile("global_load_dwordx4 %0, %1, off" : "=v"(d) : "v"(p) : "memory");
}
DEVI void wait_all(short8& a0, short8& a1, short8& a2, short8& a3,
                   short8& b0, short8& b1, short8& b2, short8& b3) {
  asm volatile("s_waitcnt vmcnt(0)"
               : "+v"(a0), "+v"(a1), "+v"(a2), "+v"(a3),
                 "+v"(b0), "+v"(b1), "+v"(b2), "+v"(b3)
               :: "memory");
}
// vmcnt retires IN ISSUE ORDER: with 8 xf loads issued before 8 h loads,
// vmcnt(8) == "the 8 xf loads are done" while the h loads stay in flight.
DEVI void wait_vmcnt8(short8& a0, short8& a1, short8& a2, short8& a3,
                      short8& b0, short8& b1, short8& b2, short8& b3) {
  asm volatile("s_waitcnt vmcnt(8)"
               : "+v"(a0), "+v"(a1), "+v"(a2), "+v"(a3),
                 "+v"(b0), "+v"(b1), "+v"(b2), "+v"(b3)
               :: "memory");
}

// fast activations: v_exp_f32 computes 2^x; v_rcp_f32 for the divide.
DEVI float fast_sigmoid(float x) {
  float e = exp2f(x * -1.44269504f);
  return __builtin_amdgcn_rcpf(1.0f + e);
}
DEVI float fast_tanh(float x) {
  float xc = fminf(fmaxf(x, -20.0f), 20.0f);   // avoid inf*(0) = NaN
  float t = exp2f(xc * -2.88539008f);
  return (1.0f - t) * __builtin_amdgcn_rcpf(1.0f + t);
}

// -------------------- fragment-layout packing kernels --------------------
// XF[t][mt4][kq16][lane64][8]  (A-frags of texts, hi/lo split)
// r7: lane remap for read coalescing — 4 consecutive lanes (same b) read
// 128 B contiguous; write goes to fragment lane lf = eo*16+bl (same bytes
// as before, permuted within the 1 KB block).
__global__ __launch_bounds__(256) void prep_xf(const float* __restrict__ x,
                                               unsigned short* __restrict__ xf_hi,
                                               unsigned short* __restrict__ xf_lo) {
  int idx = blockIdx.x * 256 + threadIdx.x;       // 512*4*16*64 = 2097152
  int lane = idx & 63;
  int kq   = (idx >> 6) & 15;
  int mt   = (idx >> 10) & 3;
  int t    = idx >> 12;
  int bl = lane >> 2;               // batch-local 0..15
  int eo = lane & 3;                // e-octet 0..3
  int b  = mt * 16 + bl;
  int e0 = kq * 32 + eo * 8;
  const float4* src = (const float4*)(x + ((size_t)b * T_LEN + t) * EMB + e0);
  float4 v0 = src[0], v1 = src[1];
  float vv[8] = {v0.x, v0.y, v0.z, v0.w, v1.x, v1.y, v1.z, v1.w};
  int lf = eo * 16 + bl;            // fragment lane position
  size_t dst = ((size_t)(idx >> 6) * 64 + lf) * 8;
#pragma unroll
  for (int i = 0; i < 8; ++i) {
    float v = vv[i];
    unsigned short hi = f32_to_bf16_rn(v);
    unsigned short lo = f32_to_bf16_rn(v - bf16_to_f32(hi));
    xf_hi[dst + i] = hi;
    xf_lo[dst + i] = lo;
  }
}

// WF[dir2][mat2][js32][nt4][kq16][lane64][8]; mat0 = Whh, mat1 = Wih
__global__ __launch_bounds__(256) void prep_wf(const float* __restrict__ whh_f,
                                               const float* __restrict__ wih_f,
                                               const float* __restrict__ whh_b,
                                               const float* __restrict__ wih_b,
                                               unsigned short* __restrict__ wf_hi,
                                               unsigned short* __restrict__ wf_lo) {
  int idx = blockIdx.x * 256 + threadIdx.x;       // 2*2*32*4*16*64 = 524288
  int lane = idx & 63;
  int kq   = (idx >> 6) & 15;
  int nt   = (idx >> 10) & 3;
  int js   = (idx >> 12) & 31;
  int mat  = (idx >> 17) & 1;
  int dir  = (idx >> 18) & 1;
  const float* W = dir ? (mat ? wih_b : whh_b) : (mat ? wih_f : whh_f);
  int row = nt * 512 + js * 16 + (lane & 15);     // gate-major rows of [2048][512]
  int k0  = kq * 32 + (lane >> 4) * 8;
  const float* src = W + (size_t)row * 512 + k0;
  size_t dst = (size_t)idx * 8;
#pragma unroll
  for (int i = 0; i < 8; ++i) {
    float v = src[i];
    unsigned short hi = f32_to_bf16_rn(v);
    unsigned short lo = f32_to_bf16_rn(v - bf16_to_f32(hi));
    wf_hi[dst + i] = hi;
    wf_lo[dst + i] = lo;
  }
}

// W2T[nt2][kq32][lane64][8]  (B-frags of W_h2t [23][1024], N padded to 32)
__global__ __launch_bounds__(256) void prep_w2t(const float* __restrict__ w2t,
                                                unsigned short* __restrict__ o_hi,
                                                unsigned short* __restrict__ o_lo) {
  int idx = blockIdx.x * 256 + threadIdx.x;       // 2*32*64 = 4096
  int lane = idx & 63;
  int kq   = (idx >> 6) & 31;
  int nt   = (idx >> 11) & 1;
  int n  = nt * 16 + (lane & 15);
  int k0 = kq * 32 + (lane >> 4) * 8;
  size_t dst = (size_t)idx * 8;
#pragma unroll
  for (int i = 0; i < 8; ++i) {
    float v = (n < NTAG) ? w2t[(size_t)n * 1024 + k0 + i] : 0.0f;
    unsigned short hi = f32_to_bf16_rn(v);
    unsigned short lo = f32_to_bf16_rn(v - bf16_to_f32(hi));
    o_hi[dst + i] = hi;
    o_lo[dst + i] = lo;
  }
}

// -------------------- sentinel fill: bf16 +inf (0x7F80) into h slots 1..512 --------
// h = sigmoid*tanh is always in (-1,1): neither hi nor lo can ever be inf, so
// "fragment word != inf-pattern" certifies the producer's 4B store has landed.
__global__ __launch_bounds__(256) void fill_sent(uint4* __restrict__ hi,
                                                 uint4* __restrict__ lo) {
  const uint4 v = {0x7F807F80u, 0x7F807F80u, 0x7F807F80u, 0x7F807F80u};
  unsigned idx = blockIdx.x * 256 + threadIdx.x;     // 1048576 threads
#pragma unroll
  for (int i = 0; i < 4; ++i) {
    unsigned k = idx + (unsigned)i * 1048576u;       // uint4 index < 4194304
    unsigned word = k << 2;                          // u32 index within 2*512 slots
    unsigned dir  = word >> 23;                      // / (512*16384)
    unsigned rem  = word & 8388607u;
    unsigned slot = 1u + (rem >> 14);                // 1..512
    unsigned off  = rem & 16383u;
    size_t dst = (((size_t)(dir * 514 + slot) << 14) + off) >> 2;  // uint4 idx
    hi[dst] = v;
    lo[dst] = v;
  }
}

// -------------------- persistent BiLSTM recurrence --------------------
// Grid = 256 WGs, 1/CU. WG = (dir, js(16 j's), bq(16 batch rows)).
// HF[dir][slot 514][bq4][kq16][lane64][8] hi/lo; slot = t+1; slots 0,513 zeroed,
// slots 1..512 sentinel-filled. Sentinel protocol (r6) + r7 issue-order
// pipelining: xf loads (L2) issued first, h loads (LLC) second; vmcnt(8)
// releases the x-GEMM while h travels; vmcnt(0)+check afterwards is usually
// free. Producers free-run (store h, no wait, no flags).
__global__ __launch_bounds__(256, 1)
void lstm_rec(const unsigned short* __restrict__ xf_hi,
              const unsigned short* __restrict__ xf_lo,
              const unsigned short* __restrict__ wf_hi,
              const unsigned short* __restrict__ wf_lo,
              const float* __restrict__ bias_f,
              const float* __restrict__ bias_b,
              unsigned short* __restrict__ hf_hi,
              unsigned short* __restrict__ hf_lo) {
  extern __shared__ unsigned char smem[];
  unsigned short* w_lds = (unsigned short*)smem;      // Whh_hi [0,64K) + Wih_hi [64K,128K)
  float* scratch = (float*)(smem + 131072);           // [wave4][nt4][lane64][4] = 16 KB

  int wg  = blockIdx.x;
  int dir = wg >> 7;
  int js  = (wg >> 2) & 31;
  int bq  = wg & 3;
  int tid  = threadIdx.x;
  int wave = tid >> 6;
  int lane = tid & 63;

  {
    const uint4* s0 = (const uint4*)wf_hi + ((size_t)(dir * 2 + 0) * 32 + js) * 4096;
    const uint4* s1 = (const uint4*)wf_hi + ((size_t)(dir * 2 + 1) * 32 + js) * 4096;
    uint4* d = (uint4*)w_lds;
    for (int i = tid; i < 4096; i += 256) { d[i] = s0[i]; d[4096 + i] = s1[i]; }
  }

  // preload step-invariant lo-weight fragments into regs/AGPRs
  short8 wlo_h[4][4], wlo_x[4][4];
#pragma unroll
  for (int q = 0; q < 4; ++q) {
    int kq = wave * 4 + q;
#pragma unroll
    for (int nt = 0; nt < 4; ++nt) {
      wlo_h[q][nt] = *(const short8*)(wf_lo +
            ((((((size_t)dir * 2 + 0) * 32 + js) * 4 + nt) * 16 + kq) * 64 + lane) * 8);
      wlo_x[q][nt] = *(const short8*)(wf_lo +
            ((((((size_t)dir * 2 + 1) * 32 + js) * 4 + nt) * 16 + kq) * 64 + lane) * 8);
    }
  }
  __syncthreads();

  int sm = tid >> 4;                 // local batch row 0..15
  int sj = tid & 15;                 // local j 0..15
  int jglob = js * 16 + sj;
  const float* bias = dir ? bias_b : bias_f;
  float bias_g[4];
#pragma unroll
  for (int g = 0; g < 4; ++g) bias_g[g] = bias[g * 512 + jglob];
  float c_state = 0.0f;

  // h write address pieces (constant per thread)
  int kqh   = jglob >> 5;
  int lane2 = ((jglob >> 3) & 3) * 16 + sm;
  int jrem  = jglob & 7;

  for (int s = 0; s < T_LEN; ++s) {
    int t = dir ? (T_LEN - 1 - s) : s;
    int rslot = dir ? (t + 2) : t;   // h[t+1] (bwd) / h[t-1] (fwd); zeros at s==0

    f32x4 acc[4];
#pragma unroll
    for (int nt = 0; nt < 4; ++nt) { f32x4 z = {0.f, 0.f, 0.f, 0.f}; acc[nt] = z; }

    const short8* bhp = (const short8*)hf_hi + ((((size_t)dir * 514 + rslot) * 4 + bq) * 16) * 64;
    const short8* blp = (const short8*)hf_lo + ((((size_t)dir * 514 + rslot) * 4 + bq) * 16) * 64;

    // issue the 8 xf loads (L2-fast) FIRST, then the 8 h loads (sc1/LLC):
    // vmcnt(8) then means "xf retired", and the h round trip rides under
    // the x-GEMM instead of being exposed after it.
    short8 xh[4], xl[4], hh[4], hl[4];
#pragma unroll
    for (int q = 0; q < 4; ++q) {
      int kq = wave * 4 + q;
      size_t xoff = ((((size_t)t * 4 + bq) * 16 + kq) * 64 + lane) * 8;
      ld_l2((const void*)(xf_hi + xoff), xh[q]);
      ld_l2((const void*)(xf_lo + xoff), xl[q]);
    }
#pragma unroll
    for (int q = 0; q < 4; ++q) {
      int kq = wave * 4 + q;
      ld_sc((const void*)(bhp + kq * 64 + lane), hh[q]);
      ld_sc((const void*)(blp + kq * 64 + lane), hl[q]);
    }
    wait_vmcnt8(xh[0], xh[1], xh[2], xh[3], xl[0], xl[1], xl[2], xl[3]);

    // x-part GEMM: Wih_hi LDS, Wih_lo regs (h loads in flight underneath)
#pragma unroll
    for (int q = 0; q < 4; ++q) {
      int kq = wave * 4 + q;
#pragma unroll
      for (int nt = 0; nt < 4; ++nt) {
        short8 bh = *(const short8*)&w_lds[((((size_t)(1 * 4 + nt)) * 16 + kq) * 64 + lane) * 8];
        acc[nt] = mfma16(xh[q], bh, acc[nt]);
        acc[nt] = mfma16(xh[q], wlo_x[q][nt], acc[nt]);
        acc[nt] = mfma16(xl[q], bh, acc[nt]);
      }
    }

    // h fragments: wait, sentinel-check, retry only if a producer lags
    {
      wait_all(hh[0], hh[1], hh[2], hh[3], hl[0], hl[1], hl[2], hl[3]);
      int guard = 0;
      for (;;) {
        uint32_t bad = 0;
#pragma unroll
        for (int q = 0; q < 4; ++q) {
          const uint32_t* wh = (const uint32_t*)&hh[q];
          const uint32_t* wl = (const uint32_t*)&hl[q];
#pragma unroll
          for (int i = 0; i < 4; ++i) {
            uint32_t x = wh[i] ^ 0x7F807F80u;
            bad |= (x - 0x00010001u) & ~x & 0x80008000u;   // zero-half <=> sentinel
            uint32_t y = wl[i] ^ 0x7F807F80u;
            bad |= (y - 0x00010001u) & ~y & 0x80008000u;
          }
        }
        if (__ballot(bad != 0) == 0ull) break;
        if (++guard > 2000000) break;
        __builtin_amdgcn_s_sleep(1);
#pragma unroll
        for (int q = 0; q < 4; ++q) {
          int kq = wave * 4 + q;
          ld_sc((const void*)(bhp + kq * 64 + lane), hh[q]);
          ld_sc((const void*)(blp + kq * 64 + lane), hl[q]);
        }
        wait_all(hh[0], hh[1], hh[2], hh[3], hl[0], hl[1], hl[2], hl[3]);
      }
    }

    // h-part GEMM: Whh_hi LDS, Whh_lo regs
#pragma unroll
    for (int q = 0; q < 4; ++q) {
      int kq = wave * 4 + q;
#pragma unroll
      for (int nt = 0; nt < 4; ++nt) {
        short8 bh = *(const short8*)&w_lds[((((size_t)(0 * 4 + nt)) * 16 + kq) * 64 + lane) * 8];
        acc[nt] = mfma16(hh[q], bh, acc[nt]);
        acc[nt] = mfma16(hh[q], wlo_h[q][nt], acc[nt]);
        acc[nt] = mfma16(hl[q], bh, acc[nt]);
      }
    }

    // cross-wave K-reduction via LDS
#pragma unroll
    for (int nt = 0; nt < 4; ++nt)
      *(f32x4*)&scratch[((size_t)(wave * 4 + nt) * 64 + lane) * 4] = acc[nt];
    __syncthreads();

    int lidx = (((sm >> 2) * 16) + sj) * 4 + (sm & 3);
    float g4[4];
#pragma unroll
    for (int g = 0; g < 4; ++g) {
      float v = bias_g[g];
#pragma unroll
      for (int w = 0; w < 4; ++w) v += scratch[(w * 4 + g) * 256 + lidx];
      g4[g] = v;
    }
    __syncthreads();                 // scratch reads done before next step's writes

    float i_s = fast_sigmoid(g4[0]);
    float f_s = fast_sigmoid(g4[1]);
    float g_t = fast_tanh(g4[2]);
    float o_s = fast_sigmoid(g4[3]);
    c_state = f_s * c_state + i_s * g_t;
    float h = o_s * fast_tanh(c_state);

    // pack neighbor pairs (sj even/odd share a 4B word), agent-scope u32 store;
    // NO wait, NO barrier, NO flag — the data itself is the signal.
    unsigned int vhi = f32_to_bf16_rn(h);
    unsigned int vlo = f32_to_bf16_rn(h - bf16_to_f32((unsigned short)vhi));
    unsigned int phi = (unsigned int)__shfl_xor((int)vhi, 1);
    unsigned int plo = (unsigned int)__shfl_xor((int)vlo, 1);
    if ((sj & 1) == 0) {
      unsigned int whi = vhi | (phi << 16);
      unsigned int wlo = vlo | (plo << 16);
      size_t foff = ((((size_t)dir * 514 + (t + 1)) * 4 + bq) * 16 + kqh);
      size_t eoff = (foff * 64 + lane2) * 8 + jrem;     // even u16 index
      __hip_atomic_store((unsigned int*)(hf_hi + eoff), whi,
                         __ATOMIC_RELAXED, __HIP_MEMORY_SCOPE_AGENT);
      __hip_atomic_store((unsigned int*)(hf_lo + eoff), wlo,
                         __ATOMIC_RELAXED, __HIP_MEMORY_SCOPE_AGENT);
    }
  }
}

// -------------------- emissions: feats = [h_f|h_b] @ W_h2t.T + b --------------------
__global__ __launch_bounds__(256) void feats_kernel(const unsigned short* __restrict__ hf_hi,
                                                    const unsigned short* __restrict__ hf_lo,
                                                    const unsigned short* __restrict__ w2t_hi,
                                                    const unsigned short* __restrict__ w2t_lo,
                                                    const float* __restrict__ b_h2t,
                                                    float* __restrict__ feats) {
  int t = blockIdx.x;
  int wave = threadIdx.x >> 6;       // = mt (batch tile)
  int lane = threadIdx.x & 63;
  f32x4 acc[2];
#pragma unroll
  for (int nt = 0; nt < 2; ++nt) { f32x4 z = {0.f, 0.f, 0.f, 0.f}; acc[nt] = z; }

  for (int kq = 0; kq < 32; ++kq) {
    int dir = kq >> 4, kqi = kq & 15;
    size_t af = (((((size_t)dir * 514 + (t + 1)) * 4 + wave) * 16 + kqi) * 64 + lane) * 8;
    short8 ah = *(const short8*)(hf_hi + af);
    short8 al = *(const short8*)(hf_lo + af);
#pragma unroll
    for (int nt = 0; nt < 2; ++nt) {
      size_t bf = (((size_t)nt * 32 + kq) * 64 + lane) * 8;
      short8 bh = *(const short8*)(w2t_hi + bf);
      short8 bl = *(const short8*)(w2t_lo + bf);
      acc[nt] = mfma16(ah, bh, acc[nt]);
      acc[nt] = mfma16(ah, bl, acc[nt]);
      acc[nt] = mfma16(al, bh, acc[nt]);
    }
  }
  int quad = lane >> 4, col = lane & 15;
#pragma unroll
  for (int nt = 0; nt < 2; ++nt) {
    int n = nt * 16 + col;
    if (n < NTAG) {
      float bb = b_h2t[n];
#pragma unroll
      for (int r = 0; r < 4; ++r) {
        int b = wave * 16 + quad * 4 + r;
        feats[((size_t)b * T_LEN + t) * 24 + n] = acc[nt][r] + bb;
      }
    }
  }
}

// -------------------- Viterbi (exact semantics; fv + trans row in registers) ----------
__global__ __launch_bounds__(64) void viterbi_kernel(const float* __restrict__ feats,
                                                     const int* __restrict__ seq_len,
                                                     const float* __restrict__ trans,
                                                     float* __restrict__ out) {
  int b = blockIdx.x;
  int lane = threadIdx.x;            // one wave per batch row
  __shared__ unsigned char bp_s[T_LEN * 24];
  bool tag_lane = lane < NTAG;
  float tr_reg[NTAG];                // tr_reg[k] = trans[next=lane][prev=k]
#pragma unroll 1
  for (int k = 0; k < NTAG; ++k) tr_reg[k] = tag_lane ? trans[lane * NTAG + k] : NEGV;
  float fv = (lane == 1) ? 0.0f : NEGV;    // START = 1; lanes >= NTAG stay NEGV
  int L = seq_len[b];
  float ft = tag_lane ? feats[((size_t)b * T_LEN) * 24 + lane] : 0.0f;
#pragma unroll 1
  for (int t = 0; t < T_LEN; ++t) {
    float ftn = 0.0f;
    if (t + 1 < T_LEN && tag_lane) ftn = feats[((size_t)b * T_LEN + t + 1) * 24 + lane];
    float best = __shfl(fv, 0) + tr_reg[0];
    int arg = 0;
#pragma unroll 1
    for (int k = 1; k < NTAG; ++k) {
      float v = __shfl(fv, k) + tr_reg[k];
      if (v > best) { best = v; arg = k; }    // strict > keeps FIRST max (jnp.argmax)
    }
    bool active = (t < L);
    if (tag_lane) bp_s[t * 24 + lane] = (unsigned char)(active ? arg : lane);
    fv = active ? (best + ft) : fv;
    ft = ftn;
  }
  // terminal: term[k] = fv[k] + trans[END][k]; argmax (first occurrence)
  float term = tag_lane ? (fv + trans[2 * NTAG + lane]) : NEGV;
  float bv = term; int bi = lane;
#pragma unroll
  for (int off = 32; off; off >>= 1) {
    float ov = __shfl_down(bv, off);
    int oi = __shfl_down(bi, off);
    if (ov > bv || (ov == bv && oi < bi)) { bv = ov; bi = oi; }
  }
  __syncthreads();                    // bp_s writes visible for the backtrack
  if (lane == 0) {
    out[b] = bv;
    int tag = bi;
    out[64 + (size_t)b * T_LEN + (T_LEN - 1)] = (float)tag;
    for (int t = T_LEN - 2; t >= 0; --t) {
      tag = bp_s[(t + 1) * 24 + tag];
      out[64 + (size_t)b * T_LEN + t] = (float)tag;
    }
  }
}

// -------------------- launch --------------------
extern "C" void kernel_launch(void* const* d_in, const int* in_sizes, int n_in,
                              void* d_out, int out_size, void* d_ws, size_t ws_size,
                              hipStream_t stream) {
  const float* texts   = (const float*)d_in[0];
  const int*   seq_len = (const int*)d_in[1];
  const float* Wih_f   = (const float*)d_in[2];
  const float* Whh_f   = (const float*)d_in[3];
  const float* b_f     = (const float*)d_in[4];
  const float* Wih_b   = (const float*)d_in[5];
  const float* Whh_b   = (const float*)d_in[6];
  const float* b_b     = (const float*)d_in[7];
  const float* W_h2t   = (const float*)d_in[8];
  const float* b_h2t   = (const float*)d_in[9];
  const float* trans   = (const float*)d_in[10];
  (void)in_sizes; (void)n_in; (void)out_size; (void)ws_size;

  unsigned char* ws = (unsigned char*)d_ws;
  size_t off = 0;
  auto alloc = [&](size_t bytes) -> void* {
    void* p = ws + off;
    off += (bytes + 255) & ~(size_t)255;
    return p;
  };
  // total ~218.4 MB — within the proven budget
  unsigned short* xf_hi  = (unsigned short*)alloc(33554432);
  unsigned short* xf_lo  = (unsigned short*)alloc(33554432);
  unsigned short* wf_hi  = (unsigned short*)alloc(8388608);
  unsigned short* wf_lo  = (unsigned short*)alloc(8388608);
  unsigned short* hf_hi  = (unsigned short*)alloc(67371008);   // 2*514*4096 frags *16B
  unsigned short* hf_lo  = (unsigned short*)alloc(67371008);
  unsigned short* w2t_hi = (unsigned short*)alloc(65536);
  unsigned short* w2t_lo = (unsigned short*)alloc(65536);
  float*          feats  = (float*)alloc(3145728);             // [64][512][24] f32

  // zero the h boundary slots (slot 0 and 513 per dir)
  for (int d = 0; d < 2; ++d) {
    hipMemsetAsync(hf_hi + ((size_t)d * 514 + 0)   * 32768, 0, 65536, stream);
    hipMemsetAsync(hf_hi + ((size_t)d * 514 + 513) * 32768, 0, 65536, stream);
    hipMemsetAsync(hf_lo + ((size_t)d * 514 + 0)   * 32768, 0, 65536, stream);
    hipMemsetAsync(hf_lo + ((size_t)d * 514 + 513) * 32768, 0, 65536, stream);
  }

  hipFuncSetAttribute((const void*)lstm_rec,
                      hipFuncAttributeMaxDynamicSharedMemorySize, 147456);

  fill_sent<<<4096, 256, 0, stream>>>((uint4*)hf_hi, (uint4*)hf_lo);
  prep_xf<<<8192, 256, 0, stream>>>(texts, xf_hi, xf_lo);
  prep_wf<<<2048, 256, 0, stream>>>(Whh_f, Wih_f, Whh_b, Wih_b, wf_hi, wf_lo);
  prep_w2t<<<16, 256, 0, stream>>>(W_h2t, w2t_hi, w2t_lo);
  lstm_rec<<<256, 256, 147456, stream>>>(xf_hi, xf_lo, wf_hi, wf_lo,
                                         b_f, b_b, hf_hi, hf_lo);
  feats_kernel<<<512, 256, 0, stream>>>(hf_hi, hf_lo, w2t_hi, w2t_lo, b_h2t, feats);
  viterbi_kernel<<<64, 64, 0, stream>>>(feats, seq_len, trans, (float*)d_out);
}